// Round 7
// baseline (357.345 us; speedup 1.0000x reference)
//
#include <hip/hip_runtime.h>
#include <hip/hip_bf16.h>
#include <math.h>

#define BB    32
#define SS    1024
#define HID   1024
#define AT    512
#define NVOC  1000
#define NT    (BB*SS)

typedef unsigned short u16;
typedef __attribute__((ext_vector_type(8))) short s16x8;   // 8 bf16 (4 VGPRs)
typedef __attribute__((ext_vector_type(4))) float f32x4;   // MFMA acc

__device__ __forceinline__ float bf2f(u16 u) {
    union { unsigned int i; float f; } x; x.i = ((unsigned int)u) << 16; return x.f;
}
__device__ __forceinline__ u16 f2bf(float f) {
    union { float f; unsigned int i; } u; u.f = f;
    unsigned int r = u.i + 0x7fffu + ((u.i >> 16) & 1u);
    return (u16)(r >> 16);
}
__device__ __forceinline__ float4 ld4(const float* p) { return *(const float4*)p; }
__device__ __forceinline__ float4 ld4bf(const u16* p) {
    ushort4 v = *(const ushort4*)p;
    return make_float4(bf2f(v.x), bf2f(v.y), bf2f(v.z), bf2f(v.w));
}
__device__ __forceinline__ void unpack8(uint4 v, float* x) {
    x[0] = bf2f((u16)(v.x & 0xffff)); x[1] = bf2f((u16)(v.x >> 16));
    x[2] = bf2f((u16)(v.y & 0xffff)); x[3] = bf2f((u16)(v.y >> 16));
    x[4] = bf2f((u16)(v.z & 0xffff)); x[5] = bf2f((u16)(v.z >> 16));
    x[6] = bf2f((u16)(v.w & 0xffff)); x[7] = bf2f((u16)(v.w >> 16));
}

// async global->LDS, 16B per lane; LDS dest = uniform base + lane*16 [m97]
__device__ __forceinline__ void gld16(const u16* g, u16* l) {
    __builtin_amdgcn_global_load_lds(
        (const __attribute__((address_space(1))) unsigned int*)g,
        (__attribute__((address_space(3))) unsigned int*)l,
        16, 0, 0);
}

struct Ptrs4f { const float* p[4]; };

__device__ __forceinline__ float blockReduceSum(float x) {
    #pragma unroll
    for (int off = 32; off > 0; off >>= 1) x += __shfl_down(x, off, 64);
    __shared__ float tmp[4];
    int lane = threadIdx.x & 63, wid = threadIdx.x >> 6;
    if (lane == 0) tmp[wid] = x;
    __syncthreads();
    if (threadIdx.x == 0) x = tmp[0] + tmp[1] + tmp[2] + tmp[3];
    return x; // valid on thread 0 only
}
__device__ __forceinline__ float waveReduceSum(float x) {
    #pragma unroll
    for (int off = 32; off > 0; off >>= 1) x += __shfl_down(x, off, 64);
    return x; // valid on lane 0
}

// ================= D1: PE16 + E16 + Wp16 + Wt transpose + W0f + zero(Wcp,CQ) ============
__global__ void k_s1(Ptrs4f E, const float* __restrict__ Wproj, Ptrs4f W,
                     const float* __restrict__ W0, const float* __restrict__ Wf,
                     u16* __restrict__ PE16, u16* __restrict__ E16o, u16* __restrict__ Wp16,
                     u16* __restrict__ Wt, float* __restrict__ W0f,
                     float* __restrict__ Wcp, float* __restrict__ CQ) {
    int blk = blockIdx.x, tid = threadIdx.x;
    if (blk < 2048) {                       // PE table bf16 (fast trig: bf16 output)
        int idx = blk*256 + tid;
        int s = idx >> 9, i = idx & 511;
        const float l2_10000 = 13.287712379549449f;
        float denom = exp2f((2.f * (float)i / 1024.f) * l2_10000);
        float ang = (float)s / denom;
        unsigned int pack = ((unsigned int)f2bf(__cosf(ang)) << 16) | f2bf(__sinf(ang));
        *(unsigned int*)(PE16 + (size_t)s*1024 + 2*i) = pack;
    } else if (blk < 4048) {                // E -> bf16
        int id2 = blk - 2048;
        int f = id2 / 500;
        int i = (id2 % 500)*256 + tid;
        E16o[(size_t)f*128000 + i] = f2bf(E.p[f][i]);
    } else if (blk < 6096) {                // Wproj -> bf16
        int i = (blk - 4048)*256 + tid;
        Wp16[i] = f2bf(Wproj[i]);
    } else if (blk < 8144) {                // W transpose -> Wt (bf16), 32x32 tiles
        int tb = blk - 6096;
        int mat = tb >> 9, t2 = tb & 511;
        int cx = t2 & 15, ry = t2 >> 4;
        int r0 = ry*32, c0 = cx*32;
        const float* in = W.p[mat];
        u16* out = Wt + (size_t)mat*1024*512;
        __shared__ float tt[32][33];
        int tx = tid & 31, ty8 = tid >> 5;
        #pragma unroll
        for (int it = 0; it < 4; ++it)
            tt[ty8 + it*8][tx] = in[(size_t)(r0 + ty8 + it*8)*512 + c0 + tx];
        __syncthreads();
        #pragma unroll
        for (int it = 0; it < 4; ++it)
            out[(size_t)(c0 + ty8 + it*8)*1024 + r0 + tx] = f2bf(tt[tx][ty8 + it*8]);
    } else if (blk < 8400) {                // W0f: wave-per-row, 4 rows/block
        int wave = tid >> 6, lane = tid & 63;
        int row = (blk - 8144)*4 + wave;
        const float* rp = W0 + (size_t)row*1024;
        float a = 0.f;
        #pragma unroll
        for (int i = 0; i < 16; ++i) {
            int j = i*64 + lane;
            a += rp[j] * Wf[j];
        }
        a = waveReduceSum(a);
        if (lane == 0) W0f[row] = a;
    } else {                                // zero Wcp (4096) + CQ (8192)
        int idx = (blk - 8400)*256 + tid;
        if (idx < 4096) Wcp[idx] = 0.f;
        else CQ[idx - 4096] = 0.f;
    }
}

// ================= D2: Wcp atomic j-split (64) + v (2048) =================
__global__ void k_s2(const float* __restrict__ Wc, const float* __restrict__ Wproj,
                     Ptrs4f W, const float* __restrict__ WV1, const float* __restrict__ WV2,
                     const float* __restrict__ W0f, float* __restrict__ Wcp, float* __restrict__ v) {
    int blk = blockIdx.x, tid = threadIdx.x;
    if (blk < 64) {                          // Wcp[c][i] += sum_{j in chunk} Wc*Wproj
        int c = blk >> 4, ic = (blk >> 2) & 3, jc = blk & 3;
        int i = ic*256 + tid;
        float a = 0.f;
        for (int j = jc*128; j < jc*128 + 128; ++j)
            a += Wc[c*512 + j] * Wproj[(size_t)(512 + j)*1024 + i];
        atomicAdd(&Wcp[c*1024 + i], a);
    } else {                                 // v
        int b2 = blk - 64;
        int h = b2 >> 10, i = b2 & 1023;
        const float* WV = h ? WV2 : WV1;
        const float* wf = W0f + h*512;
        float a = 0.f;
        for (int aa = tid; aa < 512; aa += 256) a += WV[(size_t)i*512 + aa] * wf[aa];
        a = blockReduceSum(a);
        if (tid == 0) v[h*1024 + i] = a;
    }
}

// ---------------- MFMA GEMM: C[M,N] = alpha * A[M,K] @ B[N,K]^T (bf16 in) ----------------
// 128^2 4-wave variant kept for the small preprocessing GEMMs (k_s3/k_s4).
__device__ __forceinline__ void cstore(float* p, float v) { *p = v; }
__device__ __forceinline__ void cstore(u16* p, float v)   { *p = f2bf(v); }

template<typename CT, bool CTRANS>
__device__ __forceinline__ void mfma_gemm(const u16* __restrict__ A, const u16* __restrict__ B,
                                          CT* __restrict__ C, int M, int N, int K, float alpha,
                                          int m0, int n0) {
    __shared__ u16 As[128*64];
    __shared__ u16 Bs[128*64];
    const int tid = threadIdx.x;
    const int wave = tid >> 6, lane = tid & 63;
    const int quad = lane >> 4, l16 = lane & 15;
    const int wm = (wave >> 1)*64, wn = (wave & 1)*64;
    const int srow = lane >> 3;
    const int scol = ((lane & 7) ^ srow) * 8;
    f32x4 acc[4][4] = {};

    for (int k0 = 0; k0 < K; k0 += 64) {
        #pragma unroll
        for (int p = 0; p < 4; ++p) {
            int rb = wave*32 + p*8;
            gld16(A + (size_t)(m0 + rb + srow)*K + k0 + scol, As + rb*64);
            gld16(B + (size_t)(n0 + rb + srow)*K + k0 + scol, Bs + rb*64);
        }
        __syncthreads();
        #pragma unroll
        for (int kk = 0; kk < 2; ++kk) {
            s16x8 af[4], bf[4];
            #pragma unroll
            for (int i = 0; i < 4; ++i) {
                int row = wm + i*16 + l16;
                af[i] = *(const s16x8*)(As + row*64 + (((kk*4 + quad) ^ (row & 7)) * 8));
            }
            #pragma unroll
            for (int j = 0; j < 4; ++j) {
                int row = wn + j*16 + l16;
                bf[j] = *(const s16x8*)(Bs + row*64 + (((kk*4 + quad) ^ (row & 7)) * 8));
            }
            #pragma unroll
            for (int i = 0; i < 4; ++i)
                #pragma unroll
                for (int j = 0; j < 4; ++j)
                    acc[i][j] = __builtin_amdgcn_mfma_f32_16x16x32_bf16(af[i], bf[j], acc[i][j], 0, 0, 0);
        }
        __syncthreads();
    }
    // C/D layout: col = lane&15, row = quad*4 + reg  [measured m89/m91]
    #pragma unroll
    for (int i = 0; i < 4; ++i) {
        #pragma unroll
        for (int r = 0; r < 4; ++r) {
            int gm = m0 + wm + i*16 + quad*4 + r;
            if (gm < M) {
                #pragma unroll
                for (int j = 0; j < 4; ++j) {
                    int gn = n0 + wn + j*16 + l16;
                    if (CTRANS) cstore(C + (size_t)gn*M + gm, acc[i][j][r] * alpha);
                    else        cstore(C + (size_t)gm*N + gn, acc[i][j][r] * alpha);
                }
            }
        }
    }
}

// ========= D3: PW GEMM (64) + PEQ GEMM (128) + CQ (256) + pv (1024) =====
__global__ __launch_bounds__(256) void k_s3(const u16* __restrict__ Wp16, const u16* __restrict__ Wt,
                                            u16* __restrict__ PWT,
                                            const u16* __restrict__ PE16, u16* __restrict__ PEQ16,
                                            Ptrs4f W, const float* __restrict__ Wcp, float* __restrict__ CQ,
                                            const float* __restrict__ Wproj, const float* __restrict__ v,
                                            float* __restrict__ pv) {
    int blk = blockIdx.x, tid = threadIdx.x;
    if (blk < 64) {
        int x = blk & 3, z = blk >> 2;
        int f = z >> 2, w = z & 3;
        mfma_gemm<u16,true>(Wp16 + (size_t)f*128*1024, Wt + (size_t)w*512*1024,
                            PWT + (size_t)z*512*128, 128, 512, 1024, 1.f, 0, x*128);
    } else if (blk < 192) {                  // PEQ = PE @ Wt^T  (4 w x 32 tiles)
        int idx = blk - 64;
        int w = idx >> 5, r2 = idx & 31, y = r2 >> 2, x = r2 & 3;
        mfma_gemm<u16,false>(PE16, Wt + (size_t)w*512*1024, PEQ16 + (size_t)w*1024*512,
                             1024, 512, 1024, 1.f, y*128, x*128);
    } else if (blk < 448) {
        int r = blk - 192;
        int ns = r & 1, wc = (r >> 1) & 15, jc = r >> 5;
        int w = wc & 3, c = wc >> 2; int n = ns*256 + tid;
        const float* Ww = W.p[w];
        float a = 0.f;
        for (int j = jc*128; j < jc*128 + 128; ++j) a += Wcp[c*1024 + j] * Ww[(size_t)j*512 + n];
        atomicAdd(&CQ[(size_t)(w*4 + c)*512 + n], a);
    } else {
        int b2 = blk - 448;
        int i = b2 & 127, fh = b2 >> 7; int f = fh >> 1, h = fh & 1;
        const float* row = Wproj + (size_t)(f*128 + i)*1024;
        const float* vh = v + h*1024;
        float a = 0.f;
        for (int j = tid; j < 1024; j += 256) a += row[j] * vh[j];
        a = blockReduceSum(a);
        if (tid == 0) pv[(size_t)fh*128 + i] = a;
    }
}

// ================= D4: TQK GEMMs (512) + compact dots (545) =================
__global__ __launch_bounds__(256) void k_s4(const u16* __restrict__ E16, const u16* __restrict__ PWT,
                                            const u16* __restrict__ PE16,
                                            u16* __restrict__ TQK16,
                                            const float* __restrict__ Wcp, const float* __restrict__ v,
                                            const float* __restrict__ pv,
                                            float* __restrict__ Ut, float* __restrict__ pu, float* __restrict__ cu) {
    int blk = blockIdx.x, tid = threadIdx.x;
    int wave = tid >> 6, lane = tid & 63;
    if (blk < 512) {
        int z = blk >> 5, r = blk & 31, y = r >> 2, x = r & 3;
        int f = z >> 2;
        mfma_gemm<u16,false>(E16 + (size_t)f*128000, PWT + (size_t)z*512*128,
                   TQK16 + (size_t)z*1000*512, 1000, 512, 128, 1.f, y*128, x*128);
        return;
    }
    int id = blk - 512;
    if (id < 32) {                               // Ut: one thread per (f,h,r) dot, 128-dim
        int d = id*256 + tid;
        if (d < 8000) {
            int f = d / 2000, h = (d / 1000) & 1, r = d % 1000;
            const u16* er = E16 + ((size_t)f*1000 + r)*128;
            const float* pvp = pv + (size_t)(f*2 + h)*128;
            float a = 0.f;
            #pragma unroll
            for (int q = 0; q < 16; ++q) {
                float xv[8];
                unpack8(*(const uint4*)(er + q*8), xv);
                #pragma unroll
                for (int e = 0; e < 8; ++e) a += xv[e] * pvp[q*8 + e];
            }
            Ut[(size_t)(f*2 + h)*1000 + r] = a;
        }
    } else if (id < 544) {                       // pu: wave per dot, 1024-dim
        int d = (id - 32)*4 + wave;              // 512 blocks x 4 waves = 2048 dots
        int h = d >> 10, s = d & 1023;
        float a = 0.f;
        #pragma unroll
        for (int half = 0; half < 2; ++half) {
            int k = half*512 + lane*8;
            float xv[8];
            unpack8(*(const uint4*)(PE16 + (size_t)s*1024 + k), xv);
            float4 b0 = ld4(v + h*1024 + k), b1 = ld4(v + h*1024 + k + 4);
            a += xv[0]*b0.x + xv[1]*b0.y + xv[2]*b0.z + xv[3]*b0.w
               + xv[4]*b1.x + xv[5]*b1.y + xv[6]*b1.z + xv[7]*b1.w;
        }
        a = waveReduceSum(a);
        if (lane == 0) pu[h*1024 + s] = a;
    } else {                                     // cu: 8 dots, waves do 2 each
        #pragma unroll
        for (int rep = 0; rep < 2; ++rep) {
            int d = wave*2 + rep;                // 0..7
            int h = d >> 2, c = d & 3;
            float a = 0.f;
            #pragma unroll
            for (int i = 0; i < 16; ++i) {
                int j = i*64 + lane;
                a += Wcp[c*1024 + j] * v[h*1024 + j];
            }
            a = waveReduceSum(a);
            if (lane == 0) cu[h*4 + c] = a;
        }
    }
}

// ====== scores GEMM: pair-tile stream — one block = (b, m-strip) x 2 n-tiles, 16 K-tiles =
// R7: the R2/R6 4-phase counted-vmcnt schedule unchanged, but each block now runs TWO
// n-adjacent 256^2 tiles as ONE continuous pipelined K-stream (16 tiles): the counted
// vmcnt(6) flow crosses the tile boundary (tile-9's 6 loads stay in flight during the
// half-0 epilogue), grid 512 -> 256 = exactly one grid-wave, prologue amortized 2x,
// second tile's A panel re-streams from L2. sM/sS moved to dedicated LDS (+4 KB) because
// the As/Bs buffers are live during the mid-stream epilogue.
__global__ __launch_bounds__(512, 2) void k_g_S256(
        const u16* __restrict__ Q, const u16* __restrict__ K,
        u16* __restrict__ Sb, float alpha,
        float* __restrict__ Pm, float* __restrict__ Pd, int b0) {
    __shared__ u16 As[2][16384];       // 2 x 256x64 bf16 = 64 KiB
    __shared__ u16 Bs[2][16384];       // 64 KiB
    __shared__ float sM[8][64];        // stats scratch (dedicated: Bs live mid-epilogue)
    __shared__ float sS[8][64];
    const int tid = threadIdx.x;
    const int wave = tid >> 6, lane = tid & 63;
    const int quad = lane >> 4, l16 = lane & 15;
    const int wm = wave >> 2, wn = wave & 3;         // 2M x 4N wave grid

    // bijective XCD swizzle (m204): contiguous batches per XCD
    const int nwg = (int)gridDim.x;
    int fblk = (int)blockIdx.x;
    int qq = nwg >> 3, rr = nwg & 7;
    int xcd = fblk & 7, idx = fblk >> 3;
    int swz = (xcd < rr ? xcd*(qq + 1) : rr*(qq + 1) + (xcd - rr)*qq) + idx;
    int b = swz >> 3, tile = swz & 7;                // 8 blocks per batch
    int m0 = (tile >> 1) << 8;
    int nbase = (tile & 1) << 9;                     // n-pair origin: 0 or 512

    const u16* __restrict__ Ab = Q + (size_t)b*SS*AT;
    const u16* __restrict__ Bb = K + (size_t)b*SS*AT;
    u16* __restrict__ C = Sb + (size_t)b*SS*SS;

    const int srow = lane >> 3;                 // 0..7
    const int scol = ((lane & 7) ^ srow) * 8;   // XOR k-chunk pre-swizzle (conflict-free)

    f32x4 acc[8][4] = {};

    // tile index t = 0..15: K-tile = t&7, n-half = t>>3, buffer = t&1
    auto stageA = [&](int t, int q) {
        int kt = t & 7;
        gld16(Ab + (size_t)(m0 + q*64 + wave*8 + srow)*AT + kt*64 + scol,
              &As[t & 1][q*4096 + wave*512]);
    };
    auto stageB = [&](int t, int q) {
        int kt = t & 7;
        int nn = nbase + ((t >> 3) << 8);
        gld16(Bb + (size_t)(nn + q*64 + wave*8 + srow)*AT + kt*64 + scol,
              &Bs[t & 1][q*4096 + wave*512]);
    };

    s16x8 af[4][2];          // A frags for current ih-half (reloaded at P0/P2)
    s16x8 bf[4][2];          // B frags, whole K-tile (bf[0..1] at P0, bf[2..3] at P1)

    auto readA = [&](int c, int ih) {
        #pragma unroll
        for (int i2 = 0; i2 < 4; ++i2) {
            int row = wm*128 + (ih*4 + i2)*16 + l16;
            #pragma unroll
            for (int kk = 0; kk < 2; ++kk)
                af[i2][kk] = *(const s16x8*)(&As[c][row*64 + (((kk*4 + quad) ^ (row & 7)) * 8)]);
        }
    };
    auto readB2 = [&](int c, int jh) {
        #pragma unroll
        for (int j2 = 0; j2 < 2; ++j2) {
            int j = jh*2 + j2;
            int row = wn*64 + j*16 + l16;
            #pragma unroll
            for (int kk = 0; kk < 2; ++kk)
                bf[j][kk] = *(const s16x8*)(&Bs[c][row*64 + (((kk*4 + quad) ^ (row & 7)) * 8)]);
        }
    };
    auto mma16 = [&](int ih, int jh) {         // one C-quadrant x K=64: 16 MFMA
        __builtin_amdgcn_s_setprio(1);
        #pragma unroll
        for (int i2 = 0; i2 < 4; ++i2)
            #pragma unroll
            for (int j2 = 0; j2 < 2; ++j2) {
                int i = ih*4 + i2, j = jh*2 + j2;
                acc[i][j] = __builtin_amdgcn_mfma_f32_16x16x32_bf16(af[i2][0], bf[j][0], acc[i][j], 0, 0, 0);
                acc[i][j] = __builtin_amdgcn_mfma_f32_16x16x32_bf16(af[i2][1], bf[j][1], acc[i][j], 0, 0, 0);
            }
        __builtin_amdgcn_s_setprio(0);
    };
    auto midsync = [&]() {                      // barrier, own-reads done, pin (rule 18)
        __builtin_amdgcn_s_barrier();
        asm volatile("s_waitcnt lgkmcnt(0)" ::: "memory");
        __builtin_amdgcn_sched_barrier(0);
    };

    // epilogue for one n-half: quantize + permuted store + column stats; acc NOT reset here
    auto epilogue = [&](int half) {
        int n0h = nbase + half*256;
        #pragma unroll
        for (int i = 0; i < 8; ++i) {
            #pragma unroll
            for (int r = 0; r < 4; ++r) {
                int gm = m0 + wm*128 + i*16 + quad*4 + r;
                u16 q0 = f2bf(acc[i][0][r] * alpha);
                u16 q1 = f2bf(acc[i][1][r] * alpha);
                u16 q2 = f2bf(acc[i][2][r] * alpha);
                u16 q3 = f2bf(acc[i][3][r] * alpha);
                acc[i][0][r] = bf2f(q0); acc[i][1][r] = bf2f(q1);
                acc[i][2][r] = bf2f(q2); acc[i][3][r] = bf2f(q3);
                unsigned int lo = (unsigned int)q0 | ((unsigned int)q1 << 16);
                unsigned int hi = (unsigned int)q2 | ((unsigned int)q3 << 16);
                *(uint2*)(C + (size_t)gm*SS + n0h + wn*64 + l16*4) = make_uint2(lo, hi);
            }
        }
        #pragma unroll
        for (int j = 0; j < 4; ++j) {
            float mx = -3.4e38f;
            #pragma unroll
            for (int i = 0; i < 8; ++i)
                #pragma unroll
                for (int r = 0; r < 4; ++r) mx = fmaxf(mx, acc[i][j][r]);
            mx = fmaxf(mx, __shfl_xor(mx, 16, 64));
            mx = fmaxf(mx, __shfl_xor(mx, 32, 64));
            float sm = 0.f;
            #pragma unroll
            for (int i = 0; i < 8; ++i)
                #pragma unroll
                for (int r = 0; r < 4; ++r) sm += exp2f(acc[i][j][r] - mx);
            sm += __shfl_xor(sm, 16, 64);
            sm += __shfl_xor(sm, 32, 64);
            if (quad == 0) { sM[wave][j*16 + l16] = mx; sS[wave][j*16 + l16] = sm; }
        }
        __syncthreads();
        if (tid < 256) {                 // combine the 2 row-half partials per column
            int c = tid, wq = c >> 6, cc = c & 63;
            float ma = sM[wq][cc],     sa = sS[wq][cc];
            float mb = sM[4 + wq][cc], sb2 = sS[4 + wq][cc];
            float mm = fmaxf(ma, mb);
            float ss = sa * exp2f(ma - mm) + sb2 * exp2f(mb - mm);
            size_t po = ((size_t)(b0 + b)*4 + (m0 >> 8))*1024;
            Pm[po + n0h + c] = mm;
            Pd[po + n0h + c] = ss;
        }
    };

    // prologue: tile0 all 8 chunks + tile1's first 6 (A1,A3 of tile1 go at t0.P0)
    #pragma unroll
    for (int q = 0; q < 4; ++q) stageA(0, q);
    #pragma unroll
    for (int q = 0; q < 4; ++q) stageB(0, q);
    stageA(1, 0); stageA(1, 2);
    stageB(1, 0); stageB(1, 1); stageB(1, 2); stageB(1, 3);
    asm volatile("s_waitcnt vmcnt(6)" ::: "memory");   // tile0 (oldest 8) landed
    __builtin_amdgcn_s_barrier();

    #pragma unroll 2
    for (int t = 0; t < 16; ++t) {
        const int c = t & 1;
        // ---- P0: quadrant (0,0); stage (t+1) A1,A3 (into other buffer, chunks idle)
        readA(c, 0);
        readB2(c, 0);
        if (t <= 14) { stageA(t + 1, 1); stageA(t + 1, 3); }
        midsync();
        mma16(0, 0);
        __builtin_amdgcn_s_barrier();
        // ---- P1: quadrant (0,1); stage (t+2) A0,A2 (this buffer, read-complete at P0)
        readB2(c, 1);
        if (t <= 13) { stageA(t + 2, 0); stageA(t + 2, 2); }
        midsync();
        mma16(0, 1);
        __builtin_amdgcn_s_barrier();
        // ---- P2: quadrant (1,0); stage (t+2) B0,B1 (B read-complete at P1)
        readA(c, 1);
        if (t <= 13) { stageB(t + 2, 0); stageB(t + 2, 1); }
        midsync();
        mma16(1, 0);
        __builtin_amdgcn_s_barrier();
        // ---- P3: quadrant (1,1); stage (t+2) B2,B3; tile-boundary counted vmcnt
        if (t <= 13) { stageB(t + 2, 2); stageB(t + 2, 3); }
        midsync();
        mma16(1, 1);
        if (t <= 13)      asm volatile("s_waitcnt vmcnt(6)" ::: "memory");  // t+1 landed
        else if (t == 14) asm volatile("s_waitcnt vmcnt(0)" ::: "memory");  // tile15 landed
        __builtin_amdgcn_sched_barrier(0);
        __builtin_amdgcn_s_barrier();

        if ((t & 7) == 7) {              // n-half complete: epilogue (pipeline stays hot;
            epilogue(t >> 3);            // tile t+2's 6 loads in flight, As/Bs untouched)
            if (t == 7) {                // reset accumulator for second n-tile
                #pragma unroll
                for (int i = 0; i < 8; ++i)
                    #pragma unroll
                    for (int j = 0; j < 4; ++j)
                        #pragma unroll
                        for (int r = 0; r < 4; ++r) acc[i][j][r] = 0.f;
                __syncthreads();
            }
        }
    }
}

// ---------------- gather for head h: XCD-resident n-sliced, Q+K fused per thread --------
__global__ __launch_bounds__(256) void k_gather(
                         const int* __restrict__ cate, const float* __restrict__ cont,
                         const u16* __restrict__ TQK, const float* __restrict__ CQ,
                         const u16* __restrict__ PEQ, const float* __restrict__ Ut,
                         const float* __restrict__ cu, const float* __restrict__ pu,
                         u16* __restrict__ Qh, u16* __restrict__ Kh,
                         float* __restrict__ u, int h) {
    int tid = threadIdx.x;
    int g = blockIdx.x & 7;                         // col-slice -> XCD pin
    size_t t = (size_t)(blockIdx.x >> 3)*32 + (tid >> 3);
    int cslot = tid & 7;
    int s = (int)(t & 1023);
    int4 cc = *(const int4*)(cate + t*4);
    float4 cv = ld4(cont + t*4);
    int n = g*64 + cslot*8;
    #pragma unroll
    for (int e = 0; e < 2; ++e) {                   // 0=Q, 1=K
        int w = 2*h + e;
        const u16* t0 = TQK + ((size_t)(0*4  + w)*1000 + cc.x)*512 + n;
        const u16* t1 = TQK + ((size_t)(1*4  + w)*1000 + cc.y)*512 + n;
        const u16* t2 = TQK + ((size_t)(2*4  + w)*1000 + cc.z)*512 + n;
        const u16* t3 = TQK + ((size_t)(3*4  + w)*1000 + cc.w)*512 + n;
        const u16* pq = PEQ + ((size_t)w*1024 + s)*512 + n;
        const float* cq = CQ + (size_t)w*2048 + n;
        float a0[8], a1[8], a2[8], a3[8], ap[8];
        unpack8(*(const uint4*)t0, a0); unpack8(*(const uint4*)t1, a1);
        unpack8(*(const uint4*)t2, a2); unpack8(*(const uint4*)t3, a3);
        unpack8(*(const uint4*)pq, ap);
        unsigned int pack[4];
        #pragma unroll
        for (int jp = 0; jp < 4; ++jp) {
            float x0, x1;
            #pragma unroll
            for (int half = 0; half < 2; ++half) {
                int j = jp*2 + half;
                float x = a0[j] + a1[j] + a2[j] + a3[j] + ap[j]
                        + cv.x*cq[j] + cv.y*cq[512+j] + cv.z*cq[1024+j] + cv.w*cq[1536+j];
                if (half == 0) x0 = x; else x1 = x;
            }
            pack[jp] = ((unsigned int)f2bf(x1) << 16) | f2bf(x0);
        }
        u16* op = (e ? Kh : Qh) + t*512 + n;
        *(uint4*)op = make_uint4(pack[0], pack[1], pack[2], pack[3]);
    }
    if (g == 0 && (tid & 7) == 0) {
        float uu = pu[h*1024 + s]
                 + Ut[(0*2 + h)*1000 + cc.x] + Ut[(1*2 + h)*1000 + cc.y]
                 + Ut[(2*2 + h)*1000 + cc.z] + Ut[(3*2 + h)*1000 + cc.w]
                 + cv.x*cu[h*4+0] + cv.y*cu[h*4+1] + cv.z*cu[h*4+2] + cv.w*cu[h*4+3];
        u[(size_t)h*NT + t] = uu;
    }
}

// ---------------- logits: 16 rows/block (1024 thr), inline per-batch stat combine -------
// wsm stored TRANSPOSED [8][128] (element q at [q&7][q>>3]) so the row loop reads
// wsm[i][lane+half*64] -- stride-4B across lanes, conflict-free (old ld4 at lane*32B was
// a 16-way bank conflict dominating the row's VALU work).
__global__ __launch_bounds__(1024) void k_logit(const u16* __restrict__ Sb,
                        const float* __restrict__ Pm, const float* __restrict__ Pd,
                        const float* __restrict__ u,
                        float* __restrict__ logits, float* __restrict__ out,
                        int b0, int mode) {
    __shared__ float wsm[8][128];
    int wave = threadIdx.x >> 6, lane = threadIdx.x & 63;
    size_t bi = (size_t)(gridDim.x - 1 - blockIdx.x);   // reverse: S-tail still in L2
    size_t tl0 = bi*16;
    size_t tabs0 = (size_t)b0*1024 + tl0;
    int ab = (int)(tabs0 >> 10);                        // absolute batch
    {   // inline stats: one column per thread (identical math to old k_stats_combine)
        int k = threadIdx.x;
        float mx = -3.4e38f;
        #pragma unroll
        for (int mt = 0; mt < 4; ++mt) mx = fmaxf(mx, Pm[((size_t)ab*4 + mt)*1024 + k]);
        float dd = 0.f;
        #pragma unroll
        for (int mt = 0; mt < 4; ++mt) dd += Pd[((size_t)ab*4 + mt)*1024 + k]
                                           * exp2f(Pm[((size_t)ab*4 + mt)*1024 + k] - mx);
        int q = (k & ~63) | (((k & 15) << 2) | ((k & 63) >> 4));
        wsm[q & 7][q >> 3] = u[(size_t)ab*1024 + k] / dd * exp2f(-mx);
    }
    __syncthreads();
    size_t tl = tl0 + wave;
    size_t tabs = tabs0 + wave;
    const u16* row = Sb + tl*1024;
    float acc = 0.f;
    #pragma unroll
    for (int half = 0; half < 2; ++half) {
        int k = lane*8 + half*512;
        int li = lane + half*64;
        float sv[8];
        unpack8(*(const uint4*)(row + k), sv);
        acc += exp2f(sv[0])*wsm[0][li] + exp2f(sv[1])*wsm[1][li]
             + exp2f(sv[2])*wsm[2][li] + exp2f(sv[3])*wsm[3][li]
             + exp2f(sv[4])*wsm[4][li] + exp2f(sv[5])*wsm[5][li]
             + exp2f(sv[6])*wsm[6][li] + exp2f(sv[7])*wsm[7][li];
    }
    acc = waveReduceSum(acc);
    if (lane == 0) {
        if (mode == 0) logits[tabs] = acc;
        else {
            float x = logits[tabs] + acc;
            out[tabs] = 1.f / (1.f + expf(-x));
        }
    }
}

extern "C" void kernel_launch(void* const* d_in, const int* in_sizes, int n_in,
                              void* d_out, int out_size, void* d_ws, size_t ws_size,
                              hipStream_t stream) {
    const int*   cate = (const int*)d_in[0];
    const float* cont = (const float*)d_in[1];
    Ptrs4f E; E.p[0] = (const float*)d_in[4]; E.p[1] = (const float*)d_in[5];
              E.p[2] = (const float*)d_in[6]; E.p[3] = (const float*)d_in[7];
    const float* Wc    = (const float*)d_in[8];
    const float* Wproj = (const float*)d_in[9];
    Ptrs4f W; W.p[0] = (const float*)d_in[10];  // WQ1
              W.p[1] = (const float*)d_in[11];  // WK1
              W.p[2] = (const float*)d_in[13];  // WQ2
              W.p[3] = (const float*)d_in[14];  // WK2
    const float* WV1 = (const float*)d_in[12];
    const float* WV2 = (const float*)d_in[15];
    const float* W0  = (const float*)d_in[16];
    const float* Wf  = (const float*)d_in[17];

    char* base = (char*)d_ws;
    size_t off = 0;
    auto alloc = [&](size_t bytes) { void* p = base + off; off += (bytes + 255) & ~(size_t)255; return p; };
    u16*   PE16  = (u16*)  alloc(1048576ull*2);
    u16*   E16   = (u16*)  alloc(4ull*1000*128*2);
    u16*   Wt    = (u16*)  alloc(4ull*512*1024*2);
    u16*   Wp16  = (u16*)  alloc(512ull*1024*2);
    u16*   PWT   = (u16*)  alloc(16ull*512*128*2);
    u16*   TQK16 = (u16*)  alloc(16ull*1000*512*2);
    u16*   PEQ16 = (u16*)  alloc(4ull*1024*512*2);
    float* Wcp   = (float*)alloc(4*1024*4);
    float* W0f   = (float*)alloc(1024*4);
    float* vv    = (float*)alloc(2*1024*4);
    float* CQ    = (float*)alloc(16*512*4);
    float* pvb   = (float*)alloc(8*128*4);
    float* Ut    = (float*)alloc(8*1000*4);
    float* cu    = (float*)alloc(8*4);
    float* pu    = (float*)alloc(2*1024*4);
    float* ubuf  = (float*)alloc(2ull*NT*4);
    u16*   Qh    = (u16*)  alloc((size_t)NT*512*2);
    u16*   Kh    = (u16*)  alloc((size_t)NT*512*2);
    float* Pm    = (float*)alloc(32ull*8*1024*4);
    float* Pd    = (float*)alloc(32ull*8*1024*4);
    float* logits= (float*)alloc((size_t)NT*4);
    size_t sChunkBytes = (size_t)SS*SS*2;     // bf16 S
    size_t remain = (ws_size > off) ? (ws_size - off) : 0;
    int NB = (int)(remain / sChunkBytes);
    if (NB > 32) NB = 32;
    if (NB < 1) NB = 1;
    u16* Sbuf = (u16*)(base + off);

    const float alpha = 0.06375954951107036f;   // log2(e)/sqrt(512): exp2 domain

    k_s1<<<8448, 256, 0, stream>>>(E, Wproj, W, W0, Wf, PE16, E16, Wp16, Wt, W0f, Wcp, CQ);
    k_s2<<<2112, 256, 0, stream>>>(Wc, Wproj, W, WV1, WV2, W0f, Wcp, vv);
    k_s3<<<1472, 256, 0, stream>>>(Wp16, Wt, PWT, PE16, PEQ16, W, Wcp, CQ, Wproj, vv, pvb);
    k_s4<<<1057, 256, 0, stream>>>(E16, PWT, PE16, TQK16, Wcp, vv, pvb, Ut, pu, cu);

    for (int h = 0; h < 2; ++h) {
        k_gather<<<8192, 256, 0, stream>>>(cate, cont, TQK16, CQ, PEQ16, Ut, cu, pu, Qh, Kh, ubuf, h);
        for (int b0 = 0; b0 < 32; b0 += NB) {
            int nb = (32 - b0 < NB) ? (32 - b0) : NB;
            k_g_S256<<<8*nb, 512, 0, stream>>>(Qh + (size_t)b0*SS*AT, Kh + (size_t)b0*SS*AT,
                                               Sbuf, alpha, Pm, Pd, b0);
            k_logit<<<nb*64, 1024, 0, stream>>>(Sbuf, Pm, Pd, ubuf + (size_t)h*NT,
                                                logits, (float*)d_out, b0, h);
        }
    }
}

// Round 8
// 337.754 us; speedup vs baseline: 1.0580x; 1.0580x over previous
//
#include <hip/hip_runtime.h>
#include <hip/hip_bf16.h>
#include <math.h>

#define BB    32
#define SS    1024
#define HID   1024
#define AT    512
#define NVOC  1000
#define NT    (BB*SS)

typedef unsigned short u16;
typedef __attribute__((ext_vector_type(8))) short s16x8;   // 8 bf16 (4 VGPRs)
typedef __attribute__((ext_vector_type(4))) float f32x4;   // MFMA acc

__device__ __forceinline__ float bf2f(u16 u) {
    union { unsigned int i; float f; } x; x.i = ((unsigned int)u) << 16; return x.f;
}
__device__ __forceinline__ u16 f2bf(float f) {
    union { float f; unsigned int i; } u; u.f = f;
    unsigned int r = u.i + 0x7fffu + ((u.i >> 16) & 1u);
    return (u16)(r >> 16);
}
__device__ __forceinline__ float4 ld4(const float* p) { return *(const float4*)p; }
__device__ __forceinline__ float4 ld4bf(const u16* p) {
    ushort4 v = *(const ushort4*)p;
    return make_float4(bf2f(v.x), bf2f(v.y), bf2f(v.z), bf2f(v.w));
}
__device__ __forceinline__ void unpack8(uint4 v, float* x) {
    x[0] = bf2f((u16)(v.x & 0xffff)); x[1] = bf2f((u16)(v.x >> 16));
    x[2] = bf2f((u16)(v.y & 0xffff)); x[3] = bf2f((u16)(v.y >> 16));
    x[4] = bf2f((u16)(v.z & 0xffff)); x[5] = bf2f((u16)(v.z >> 16));
    x[6] = bf2f((u16)(v.w & 0xffff)); x[7] = bf2f((u16)(v.w >> 16));
}

// async global->LDS, 16B per lane; LDS dest = uniform base + lane*16 [m97]
__device__ __forceinline__ void gld16(const u16* g, u16* l) {
    __builtin_amdgcn_global_load_lds(
        (const __attribute__((address_space(1))) unsigned int*)g,
        (__attribute__((address_space(3))) unsigned int*)l,
        16, 0, 0);
}

struct Ptrs4f { const float* p[4]; };

__device__ __forceinline__ float blockReduceSum(float x) {
    #pragma unroll
    for (int off = 32; off > 0; off >>= 1) x += __shfl_down(x, off, 64);
    __shared__ float tmp[4];
    int lane = threadIdx.x & 63, wid = threadIdx.x >> 6;
    if (lane == 0) tmp[wid] = x;
    __syncthreads();
    if (threadIdx.x == 0) x = tmp[0] + tmp[1] + tmp[2] + tmp[3];
    return x; // valid on thread 0 only
}
__device__ __forceinline__ float waveReduceSum(float x) {
    #pragma unroll
    for (int off = 32; off > 0; off >>= 1) x += __shfl_down(x, off, 64);
    return x; // valid on lane 0
}

// ================= D1: PE16 + E16 + Wp16 + Wt transpose + W0f + zero(Wcp,CQ) ============
__global__ void k_s1(Ptrs4f E, const float* __restrict__ Wproj, Ptrs4f W,
                     const float* __restrict__ W0, const float* __restrict__ Wf,
                     u16* __restrict__ PE16, u16* __restrict__ E16o, u16* __restrict__ Wp16,
                     u16* __restrict__ Wt, float* __restrict__ W0f,
                     float* __restrict__ Wcp, float* __restrict__ CQ) {
    int blk = blockIdx.x, tid = threadIdx.x;
    if (blk < 2048) {                       // PE table bf16 (fast trig: bf16 output)
        int idx = blk*256 + tid;
        int s = idx >> 9, i = idx & 511;
        const float l2_10000 = 13.287712379549449f;
        float denom = exp2f((2.f * (float)i / 1024.f) * l2_10000);
        float ang = (float)s / denom;
        unsigned int pack = ((unsigned int)f2bf(__cosf(ang)) << 16) | f2bf(__sinf(ang));
        *(unsigned int*)(PE16 + (size_t)s*1024 + 2*i) = pack;
    } else if (blk < 4048) {                // E -> bf16
        int id2 = blk - 2048;
        int f = id2 / 500;
        int i = (id2 % 500)*256 + tid;
        E16o[(size_t)f*128000 + i] = f2bf(E.p[f][i]);
    } else if (blk < 6096) {                // Wproj -> bf16
        int i = (blk - 4048)*256 + tid;
        Wp16[i] = f2bf(Wproj[i]);
    } else if (blk < 8144) {                // W transpose -> Wt (bf16), 32x32 tiles
        int tb = blk - 6096;
        int mat = tb >> 9, t2 = tb & 511;
        int cx = t2 & 15, ry = t2 >> 4;
        int r0 = ry*32, c0 = cx*32;
        const float* in = W.p[mat];
        u16* out = Wt + (size_t)mat*1024*512;
        __shared__ float tt[32][33];
        int tx = tid & 31, ty8 = tid >> 5;
        #pragma unroll
        for (int it = 0; it < 4; ++it)
            tt[ty8 + it*8][tx] = in[(size_t)(r0 + ty8 + it*8)*512 + c0 + tx];
        __syncthreads();
        #pragma unroll
        for (int it = 0; it < 4; ++it)
            out[(size_t)(c0 + ty8 + it*8)*1024 + r0 + tx] = f2bf(tt[tx][ty8 + it*8]);
    } else if (blk < 8400) {                // W0f: wave-per-row, 4 rows/block
        int wave = tid >> 6, lane = tid & 63;
        int row = (blk - 8144)*4 + wave;
        const float* rp = W0 + (size_t)row*1024;
        float a = 0.f;
        #pragma unroll
        for (int i = 0; i < 16; ++i) {
            int j = i*64 + lane;
            a += rp[j] * Wf[j];
        }
        a = waveReduceSum(a);
        if (lane == 0) W0f[row] = a;
    } else {                                // zero Wcp (4096) + CQ (8192)
        int idx = (blk - 8400)*256 + tid;
        if (idx < 4096) Wcp[idx] = 0.f;
        else CQ[idx - 4096] = 0.f;
    }
}

// ================= D2: Wcp atomic j-split (64) + v (2048) =================
__global__ void k_s2(const float* __restrict__ Wc, const float* __restrict__ Wproj,
                     Ptrs4f W, const float* __restrict__ WV1, const float* __restrict__ WV2,
                     const float* __restrict__ W0f, float* __restrict__ Wcp, float* __restrict__ v) {
    int blk = blockIdx.x, tid = threadIdx.x;
    if (blk < 64) {                          // Wcp[c][i] += sum_{j in chunk} Wc*Wproj
        int c = blk >> 4, ic = (blk >> 2) & 3, jc = blk & 3;
        int i = ic*256 + tid;
        float a = 0.f;
        for (int j = jc*128; j < jc*128 + 128; ++j)
            a += Wc[c*512 + j] * Wproj[(size_t)(512 + j)*1024 + i];
        atomicAdd(&Wcp[c*1024 + i], a);
    } else {                                 // v
        int b2 = blk - 64;
        int h = b2 >> 10, i = b2 & 1023;
        const float* WV = h ? WV2 : WV1;
        const float* wf = W0f + h*512;
        float a = 0.f;
        for (int aa = tid; aa < 512; aa += 256) a += WV[(size_t)i*512 + aa] * wf[aa];
        a = blockReduceSum(a);
        if (tid == 0) v[h*1024 + i] = a;
    }
}

// ---------------- MFMA GEMM: C[M,N] = alpha * A[M,K] @ B[N,K]^T (bf16 in) ----------------
// 128^2 4-wave variant kept for the small preprocessing GEMMs (k_s3/k_s4).
__device__ __forceinline__ void cstore(float* p, float v) { *p = v; }
__device__ __forceinline__ void cstore(u16* p, float v)   { *p = f2bf(v); }

template<typename CT, bool CTRANS>
__device__ __forceinline__ void mfma_gemm(const u16* __restrict__ A, const u16* __restrict__ B,
                                          CT* __restrict__ C, int M, int N, int K, float alpha,
                                          int m0, int n0) {
    __shared__ u16 As[128*64];
    __shared__ u16 Bs[128*64];
    const int tid = threadIdx.x;
    const int wave = tid >> 6, lane = tid & 63;
    const int quad = lane >> 4, l16 = lane & 15;
    const int wm = (wave >> 1)*64, wn = (wave & 1)*64;
    const int srow = lane >> 3;
    const int scol = ((lane & 7) ^ srow) * 8;
    f32x4 acc[4][4] = {};

    for (int k0 = 0; k0 < K; k0 += 64) {
        #pragma unroll
        for (int p = 0; p < 4; ++p) {
            int rb = wave*32 + p*8;
            gld16(A + (size_t)(m0 + rb + srow)*K + k0 + scol, As + rb*64);
            gld16(B + (size_t)(n0 + rb + srow)*K + k0 + scol, Bs + rb*64);
        }
        __syncthreads();
        #pragma unroll
        for (int kk = 0; kk < 2; ++kk) {
            s16x8 af[4], bf[4];
            #pragma unroll
            for (int i = 0; i < 4; ++i) {
                int row = wm + i*16 + l16;
                af[i] = *(const s16x8*)(As + row*64 + (((kk*4 + quad) ^ (row & 7)) * 8));
            }
            #pragma unroll
            for (int j = 0; j < 4; ++j) {
                int row = wn + j*16 + l16;
                bf[j] = *(const s16x8*)(Bs + row*64 + (((kk*4 + quad) ^ (row & 7)) * 8));
            }
            #pragma unroll
            for (int i = 0; i < 4; ++i)
                #pragma unroll
                for (int j = 0; j < 4; ++j)
                    acc[i][j] = __builtin_amdgcn_mfma_f32_16x16x32_bf16(af[i], bf[j], acc[i][j], 0, 0, 0);
        }
        __syncthreads();
    }
    // C/D layout: col = lane&15, row = quad*4 + reg  [measured m89/m91]
    #pragma unroll
    for (int i = 0; i < 4; ++i) {
        #pragma unroll
        for (int r = 0; r < 4; ++r) {
            int gm = m0 + wm + i*16 + quad*4 + r;
            if (gm < M) {
                #pragma unroll
                for (int j = 0; j < 4; ++j) {
                    int gn = n0 + wn + j*16 + l16;
                    if (CTRANS) cstore(C + (size_t)gn*M + gm, acc[i][j][r] * alpha);
                    else        cstore(C + (size_t)gm*N + gn, acc[i][j][r] * alpha);
                }
            }
        }
    }
}

// ========= D3: PW GEMM (64) + PEQ GEMM (128) + CQ (256) + pv (1024) =====
__global__ __launch_bounds__(256) void k_s3(const u16* __restrict__ Wp16, const u16* __restrict__ Wt,
                                            u16* __restrict__ PWT,
                                            const u16* __restrict__ PE16, u16* __restrict__ PEQ16,
                                            Ptrs4f W, const float* __restrict__ Wcp, float* __restrict__ CQ,
                                            const float* __restrict__ Wproj, const float* __restrict__ v,
                                            float* __restrict__ pv) {
    int blk = blockIdx.x, tid = threadIdx.x;
    if (blk < 64) {
        int x = blk & 3, z = blk >> 2;
        int f = z >> 2, w = z & 3;
        mfma_gemm<u16,true>(Wp16 + (size_t)f*128*1024, Wt + (size_t)w*512*1024,
                            PWT + (size_t)z*512*128, 128, 512, 1024, 1.f, 0, x*128);
    } else if (blk < 192) {                  // PEQ = PE @ Wt^T  (4 w x 32 tiles)
        int idx = blk - 64;
        int w = idx >> 5, r2 = idx & 31, y = r2 >> 2, x = r2 & 3;
        mfma_gemm<u16,false>(PE16, Wt + (size_t)w*512*1024, PEQ16 + (size_t)w*1024*512,
                             1024, 512, 1024, 1.f, y*128, x*128);
    } else if (blk < 448) {
        int r = blk - 192;
        int ns = r & 1, wc = (r >> 1) & 15, jc = r >> 5;
        int w = wc & 3, c = wc >> 2; int n = ns*256 + tid;
        const float* Ww = W.p[w];
        float a = 0.f;
        for (int j = jc*128; j < jc*128 + 128; ++j) a += Wcp[c*1024 + j] * Ww[(size_t)j*512 + n];
        atomicAdd(&CQ[(size_t)(w*4 + c)*512 + n], a);
    } else {
        int b2 = blk - 448;
        int i = b2 & 127, fh = b2 >> 7; int f = fh >> 1, h = fh & 1;
        const float* row = Wproj + (size_t)(f*128 + i)*1024;
        const float* vh = v + h*1024;
        float a = 0.f;
        for (int j = tid; j < 1024; j += 256) a += row[j] * vh[j];
        a = blockReduceSum(a);
        if (tid == 0) pv[(size_t)fh*128 + i] = a;
    }
}

// ================= D4: TQK GEMMs (512) + compact dots (545) =================
__global__ __launch_bounds__(256) void k_s4(const u16* __restrict__ E16, const u16* __restrict__ PWT,
                                            const u16* __restrict__ PE16,
                                            u16* __restrict__ TQK16,
                                            const float* __restrict__ Wcp, const float* __restrict__ v,
                                            const float* __restrict__ pv,
                                            float* __restrict__ Ut, float* __restrict__ pu, float* __restrict__ cu) {
    int blk = blockIdx.x, tid = threadIdx.x;
    int wave = tid >> 6, lane = tid & 63;
    if (blk < 512) {
        int z = blk >> 5, r = blk & 31, y = r >> 2, x = r & 3;
        int f = z >> 2;
        mfma_gemm<u16,false>(E16 + (size_t)f*128000, PWT + (size_t)z*512*128,
                   TQK16 + (size_t)z*1000*512, 1000, 512, 128, 1.f, y*128, x*128);
        return;
    }
    int id = blk - 512;
    if (id < 32) {                               // Ut: one thread per (f,h,r) dot, 128-dim
        int d = id*256 + tid;
        if (d < 8000) {
            int f = d / 2000, h = (d / 1000) & 1, r = d % 1000;
            const u16* er = E16 + ((size_t)f*1000 + r)*128;
            const float* pvp = pv + (size_t)(f*2 + h)*128;
            float a = 0.f;
            #pragma unroll
            for (int q = 0; q < 16; ++q) {
                float xv[8];
                unpack8(*(const uint4*)(er + q*8), xv);
                #pragma unroll
                for (int e = 0; e < 8; ++e) a += xv[e] * pvp[q*8 + e];
            }
            Ut[(size_t)(f*2 + h)*1000 + r] = a;
        }
    } else if (id < 544) {                       // pu: wave per dot, 1024-dim
        int d = (id - 32)*4 + wave;              // 512 blocks x 4 waves = 2048 dots
        int h = d >> 10, s = d & 1023;
        float a = 0.f;
        #pragma unroll
        for (int half = 0; half < 2; ++half) {
            int k = half*512 + lane*8;
            float xv[8];
            unpack8(*(const uint4*)(PE16 + (size_t)s*1024 + k), xv);
            float4 b0 = ld4(v + h*1024 + k), b1 = ld4(v + h*1024 + k + 4);
            a += xv[0]*b0.x + xv[1]*b0.y + xv[2]*b0.z + xv[3]*b0.w
               + xv[4]*b1.x + xv[5]*b1.y + xv[6]*b1.z + xv[7]*b1.w;
        }
        a = waveReduceSum(a);
        if (lane == 0) pu[h*1024 + s] = a;
    } else {                                     // cu: 8 dots, waves do 2 each
        #pragma unroll
        for (int rep = 0; rep < 2; ++rep) {
            int d = wave*2 + rep;                // 0..7
            int h = d >> 2, c = d & 3;
            float a = 0.f;
            #pragma unroll
            for (int i = 0; i < 16; ++i) {
                int j = i*64 + lane;
                a += Wcp[c*1024 + j] * v[h*1024 + j];
            }
            a = waveReduceSum(a);
            if (lane == 0) cu[h*4 + c] = a;
        }
    }
}

// ================= scores GEMM, 256^2 tile / 8 waves / 8-phase schedule (R2/R6, 52us) ====
// R7's pair-tile stream regressed (92us: mid-stream epilogue stall + broken L2 sharing);
// reverted byte-for-byte to the proven R6 single-tile version. S-GEMM is closed.
__global__ __launch_bounds__(512, 2) void k_g_S256(
        const u16* __restrict__ Q, const u16* __restrict__ K,
        u16* __restrict__ Sb, float alpha,
        float* __restrict__ Pm, float* __restrict__ Pd, int b0) {
    __shared__ u16 As[2][16384];       // 2 x 256x64 bf16 = 64 KiB
    __shared__ u16 Bs[2][16384];       // 64 KiB  (total 128 KiB -> 1 block/CU, 8 waves)
    const int tid = threadIdx.x;
    const int wave = tid >> 6, lane = tid & 63;
    const int quad = lane >> 4, l16 = lane & 15;
    const int wm = wave >> 2, wn = wave & 3;         // 2M x 4N wave grid

    // bijective XCD swizzle (m204)
    const int nwg = (int)gridDim.x;
    int fblk = (int)blockIdx.x;
    int qq = nwg >> 3, rr = nwg & 7;
    int xcd = fblk & 7, idx = fblk >> 3;
    int swz = (xcd < rr ? xcd*(qq + 1) : rr*(qq + 1) + (xcd - rr)*qq) + idx;
    int b = swz >> 4, tile = swz & 15;
    int m0 = (tile >> 2) << 8, n0 = (tile & 3) << 8;

    const u16* __restrict__ Ab = Q + (size_t)b*SS*AT;
    const u16* __restrict__ Bb = K + (size_t)b*SS*AT;
    u16* __restrict__ C = Sb + (size_t)b*SS*SS;

    const int srow = lane >> 3;                 // 0..7
    const int scol = ((lane & 7) ^ srow) * 8;   // XOR k-chunk pre-swizzle (conflict-free)

    f32x4 acc[8][4] = {};

    // stage one 64-row chunk (q=0..3) of A or B for K-tile kt into buf kt&1 (1 gld16/thread)
    auto stageA = [&](int kt, int q) {
        gld16(Ab + (size_t)(m0 + q*64 + wave*8 + srow)*AT + kt*64 + scol,
              &As[kt & 1][q*4096 + wave*512]);
    };
    auto stageB = [&](int kt, int q) {
        gld16(Bb + (size_t)(n0 + q*64 + wave*8 + srow)*AT + kt*64 + scol,
              &Bs[kt & 1][q*4096 + wave*512]);
    };

    s16x8 af[4][2];          // A frags for current ih-half (reloaded at P0/P2)
    s16x8 bf[4][2];          // B frags, whole K-tile (bf[0..1] at P0, bf[2..3] at P1)

    auto readA = [&](int c, int ih) {
        #pragma unroll
        for (int i2 = 0; i2 < 4; ++i2) {
            int row = wm*128 + (ih*4 + i2)*16 + l16;
            #pragma unroll
            for (int kk = 0; kk < 2; ++kk)
                af[i2][kk] = *(const s16x8*)(&As[c][row*64 + (((kk*4 + quad) ^ (row & 7)) * 8)]);
        }
    };
    auto readB2 = [&](int c, int jh) {
        #pragma unroll
        for (int j2 = 0; j2 < 2; ++j2) {
            int j = jh*2 + j2;
            int row = wn*64 + j*16 + l16;
            #pragma unroll
            for (int kk = 0; kk < 2; ++kk)
                bf[j][kk] = *(const s16x8*)(&Bs[c][row*64 + (((kk*4 + quad) ^ (row & 7)) * 8)]);
        }
    };
    auto mma16 = [&](int ih, int jh) {         // one C-quadrant x K=64: 16 MFMA
        __builtin_amdgcn_s_setprio(1);
        #pragma unroll
        for (int i2 = 0; i2 < 4; ++i2)
            #pragma unroll
            for (int j2 = 0; j2 < 2; ++j2) {
                int i = ih*4 + i2, j = jh*2 + j2;
                acc[i][j] = __builtin_amdgcn_mfma_f32_16x16x32_bf16(af[i2][0], bf[j][0], acc[i][j], 0, 0, 0);
                acc[i][j] = __builtin_amdgcn_mfma_f32_16x16x32_bf16(af[i2][1], bf[j][1], acc[i][j], 0, 0, 0);
            }
        __builtin_amdgcn_s_setprio(0);
    };
    auto midsync = [&]() {                      // barrier, own-reads done, pin (rule 18)
        __builtin_amdgcn_s_barrier();
        asm volatile("s_waitcnt lgkmcnt(0)" ::: "memory");
        __builtin_amdgcn_sched_barrier(0);
    };

    // prologue: tile0 all 8 chunks + tile1's first 6 (A1,A3 of tile1 go at t0.P0)
    #pragma unroll
    for (int q = 0; q < 4; ++q) stageA(0, q);
    #pragma unroll
    for (int q = 0; q < 4; ++q) stageB(0, q);
    stageA(1, 0); stageA(1, 2);
    stageB(1, 0); stageB(1, 1); stageB(1, 2); stageB(1, 3);
    asm volatile("s_waitcnt vmcnt(6)" ::: "memory");   // tile0 (oldest 8) landed
    __builtin_amdgcn_s_barrier();

    #pragma unroll
    for (int t = 0; t < 8; ++t) {
        const int c = t & 1;
        // ---- P0: quadrant (ih=0, jh=0); 12 ds_reads; stage (t+1) A1,A3 -> idle buffer
        readA(c, 0);
        readB2(c, 0);
        if (t <= 6) { stageA(t + 1, 1); stageA(t + 1, 3); }
        midsync();
        mma16(0, 0);
        __builtin_amdgcn_s_barrier();
        // ---- P1: quadrant (0,1); 4 ds_reads; stage (t+2) A0,A2 (free since end P0)
        readB2(c, 1);
        if (t <= 5) { stageA(t + 2, 0); stageA(t + 2, 2); }
        midsync();
        mma16(0, 1);
        __builtin_amdgcn_s_barrier();
        // ---- P2: quadrant (1,0); 8 ds_reads; stage (t+2) B0,B1 (B free since end P1)
        readA(c, 1);
        if (t <= 5) { stageB(t + 2, 0); stageB(t + 2, 1); }
        midsync();
        mma16(1, 0);
        __builtin_amdgcn_s_barrier();
        // ---- P3: quadrant (1,1); stage (t+2) B2,B3; tile-boundary counted vmcnt
        if (t <= 5) { stageB(t + 2, 2); stageB(t + 2, 3); }
        midsync();
        mma16(1, 1);
        if (t <= 5)      asm volatile("s_waitcnt vmcnt(6)" ::: "memory");  // t+1 landed
        else if (t == 6) asm volatile("s_waitcnt vmcnt(0)" ::: "memory");  // tile7 landed
        __builtin_amdgcn_sched_barrier(0);
        __builtin_amdgcn_s_barrier();
    }

    // epilogue: quantize once, permuted 8B stores, per-tile column max+sum stats
    #pragma unroll
    for (int i = 0; i < 8; ++i) {
        #pragma unroll
        for (int r = 0; r < 4; ++r) {
            int gm = m0 + wm*128 + i*16 + quad*4 + r;
            u16 q0 = f2bf(acc[i][0][r] * alpha);
            u16 q1 = f2bf(acc[i][1][r] * alpha);
            u16 q2 = f2bf(acc[i][2][r] * alpha);
            u16 q3 = f2bf(acc[i][3][r] * alpha);
            acc[i][0][r] = bf2f(q0); acc[i][1][r] = bf2f(q1);
            acc[i][2][r] = bf2f(q2); acc[i][3][r] = bf2f(q3);
            unsigned int lo = (unsigned int)q0 | ((unsigned int)q1 << 16);
            unsigned int hi = (unsigned int)q2 | ((unsigned int)q3 << 16);
            *(uint2*)(C + (size_t)gm*SS + n0 + wn*64 + l16*4) = make_uint2(lo, hi);
        }
    }
    // per-wave stats over its 128 rows; LDS (loop done) reused for the combine
    float* sM = (float*)&As[0][0];
    float* sS = (float*)&Bs[0][0];
    #pragma unroll
    for (int j = 0; j < 4; ++j) {
        float mx = -3.4e38f;
        #pragma unroll
        for (int i = 0; i < 8; ++i)
            #pragma unroll
            for (int r = 0; r < 4; ++r) mx = fmaxf(mx, acc[i][j][r]);
        mx = fmaxf(mx, __shfl_xor(mx, 16, 64));
        mx = fmaxf(mx, __shfl_xor(mx, 32, 64));
        float sm = 0.f;
        #pragma unroll
        for (int i = 0; i < 8; ++i)
            #pragma unroll
            for (int r = 0; r < 4; ++r) sm += exp2f(acc[i][j][r] - mx);
        sm += __shfl_xor(sm, 16, 64);
        sm += __shfl_xor(sm, 32, 64);
        if (quad == 0) { sM[wave*64 + j*16 + l16] = mx; sS[wave*64 + j*16 + l16] = sm; }
    }
    __syncthreads();
    if (tid < 256) {                     // combine the 2 row-half partials per column
        int c = tid, wq = c >> 6, cc = c & 63;
        float ma = sM[wq*64 + cc],       sa = sS[wq*64 + cc];
        float mb = sM[(4 + wq)*64 + cc], sb2 = sS[(4 + wq)*64 + cc];
        float mm = fmaxf(ma, mb);
        float ss = sa * exp2f(ma - mm) + sb2 * exp2f(mb - mm);
        size_t po = ((size_t)(b0 + b)*4 + (m0 >> 8))*1024;
        Pm[po + n0 + c] = mm;
        Pd[po + n0 + c] = ss;
    }
}

// ---------------- gather for head h: XCD-resident n-sliced, Q+K fused per thread --------
__global__ __launch_bounds__(256) void k_gather(
                         const int* __restrict__ cate, const float* __restrict__ cont,
                         const u16* __restrict__ TQK, const float* __restrict__ CQ,
                         const u16* __restrict__ PEQ, const float* __restrict__ Ut,
                         const float* __restrict__ cu, const float* __restrict__ pu,
                         u16* __restrict__ Qh, u16* __restrict__ Kh,
                         float* __restrict__ u, int h) {
    int tid = threadIdx.x;
    int g = blockIdx.x & 7;                         // col-slice -> XCD pin
    size_t t = (size_t)(blockIdx.x >> 3)*32 + (tid >> 3);
    int cslot = tid & 7;
    int s = (int)(t & 1023);
    int4 cc = *(const int4*)(cate + t*4);
    float4 cv = ld4(cont + t*4);
    int n = g*64 + cslot*8;
    #pragma unroll
    for (int e = 0; e < 2; ++e) {                   // 0=Q, 1=K
        int w = 2*h + e;
        const u16* t0 = TQK + ((size_t)(0*4  + w)*1000 + cc.x)*512 + n;
        const u16* t1 = TQK + ((size_t)(1*4  + w)*1000 + cc.y)*512 + n;
        const u16* t2 = TQK + ((size_t)(2*4  + w)*1000 + cc.z)*512 + n;
        const u16* t3 = TQK + ((size_t)(3*4  + w)*1000 + cc.w)*512 + n;
        const u16* pq = PEQ + ((size_t)w*1024 + s)*512 + n;
        const float* cq = CQ + (size_t)w*2048 + n;
        float a0[8], a1[8], a2[8], a3[8], ap[8];
        unpack8(*(const uint4*)t0, a0); unpack8(*(const uint4*)t1, a1);
        unpack8(*(const uint4*)t2, a2); unpack8(*(const uint4*)t3, a3);
        unpack8(*(const uint4*)pq, ap);
        unsigned int pack[4];
        #pragma unroll
        for (int jp = 0; jp < 4; ++jp) {
            float x0, x1;
            #pragma unroll
            for (int half = 0; half < 2; ++half) {
                int j = jp*2 + half;
                float x = a0[j] + a1[j] + a2[j] + a3[j] + ap[j]
                        + cv.x*cq[j] + cv.y*cq[512+j] + cv.z*cq[1024+j] + cv.w*cq[1536+j];
                if (half == 0) x0 = x; else x1 = x;
            }
            pack[jp] = ((unsigned int)f2bf(x1) << 16) | f2bf(x0);
        }
        u16* op = (e ? Kh : Qh) + t*512 + n;
        *(uint4*)op = make_uint4(pack[0], pack[1], pack[2], pack[3]);
    }
    if (g == 0 && (tid & 7) == 0) {
        float uu = pu[h*1024 + s]
                 + Ut[(0*2 + h)*1000 + cc.x] + Ut[(1*2 + h)*1000 + cc.y]
                 + Ut[(2*2 + h)*1000 + cc.z] + Ut[(3*2 + h)*1000 + cc.w]
                 + cv.x*cu[h*4+0] + cv.y*cu[h*4+1] + cv.z*cu[h*4+2] + cv.w*cu[h*4+3];
        u[(size_t)h*NT + t] = uu;
    }
}

// ---------------- logits: 16 rows/block (1024 thr), inline per-batch stat combine -------
// wsm stored TRANSPOSED [8][128] (element q at [q&7][q>>3]) so the row loop reads
// wsm[i][lane+half*64] -- stride-4B across lanes, conflict-free. (R7-proven: this fix
// cut the per-head logit pass by ~30us vs the lane*32B ld4 16-way-conflict layout.)
__global__ __launch_bounds__(1024) void k_logit(const u16* __restrict__ Sb,
                        const float* __restrict__ Pm, const float* __restrict__ Pd,
                        const float* __restrict__ u,
                        float* __restrict__ logits, float* __restrict__ out,
                        int b0, int mode) {
    __shared__ float wsm[8][128];
    int wave = threadIdx.x >> 6, lane = threadIdx.x & 63;
    size_t bi = (size_t)(gridDim.x - 1 - blockIdx.x);   // reverse: S-tail still in L2
    size_t tl0 = bi*16;
    size_t tabs0 = (size_t)b0*1024 + tl0;
    int ab = (int)(tabs0 >> 10);                        // absolute batch
    {   // inline stats: one column per thread (identical math to old k_stats_combine)
        int k = threadIdx.x;
        float mx = -3.4e38f;
        #pragma unroll
        for (int mt = 0; mt < 4; ++mt) mx = fmaxf(mx, Pm[((size_t)ab*4 + mt)*1024 + k]);
        float dd = 0.f;
        #pragma unroll
        for (int mt = 0; mt < 4; ++mt) dd += Pd[((size_t)ab*4 + mt)*1024 + k]
                                           * exp2f(Pm[((size_t)ab*4 + mt)*1024 + k] - mx);
        int q = (k & ~63) | (((k & 15) << 2) | ((k & 63) >> 4));
        wsm[q & 7][q >> 3] = u[(size_t)ab*1024 + k] / dd * exp2f(-mx);
    }
    __syncthreads();
    size_t tl = tl0 + wave;
    size_t tabs = tabs0 + wave;
    const u16* row = Sb + tl*1024;
    float acc = 0.f;
    #pragma unroll
    for (int half = 0; half < 2; ++half) {
        int k = lane*8 + half*512;
        int li = lane + half*64;
        float sv[8];
        unpack8(*(const uint4*)(row + k), sv);
        acc += exp2f(sv[0])*wsm[0][li] + exp2f(sv[1])*wsm[1][li]
             + exp2f(sv[2])*wsm[2][li] + exp2f(sv[3])*wsm[3][li]
             + exp2f(sv[4])*wsm[4][li] + exp2f(sv[5])*wsm[5][li]
             + exp2f(sv[6])*wsm[6][li] + exp2f(sv[7])*wsm[7][li];
    }
    acc = waveReduceSum(acc);
    if (lane == 0) {
        if (mode == 0) logits[tabs] = acc;
        else {
            float x = logits[tabs] + acc;
            out[tabs] = 1.f / (1.f + expf(-x));
        }
    }
}

extern "C" void kernel_launch(void* const* d_in, const int* in_sizes, int n_in,
                              void* d_out, int out_size, void* d_ws, size_t ws_size,
                              hipStream_t stream) {
    const int*   cate = (const int*)d_in[0];
    const float* cont = (const float*)d_in[1];
    Ptrs4f E; E.p[0] = (const float*)d_in[4]; E.p[1] = (const float*)d_in[5];
              E.p[2] = (const float*)d_in[6]; E.p[3] = (const float*)d_in[7];
    const float* Wc    = (const float*)d_in[8];
    const float* Wproj = (const float*)d_in[9];
    Ptrs4f W; W.p[0] = (const float*)d_in[10];  // WQ1
              W.p[1] = (const float*)d_in[11];  // WK1
              W.p[2] = (const float*)d_in[13];  // WQ2
              W.p[3] = (const float*)d_in[14];  // WK2
    const float* WV1 = (const float*)d_in[12];
    const float* WV2 = (const float*)d_in[15];
    const float* W0  = (const float*)d_in[16];
    const float* Wf  = (const float*)d_in[17];

    char* base = (char*)d_ws;
    size_t off = 0;
    auto alloc = [&](size_t bytes) { void* p = base + off; off += (bytes + 255) & ~(size_t)255; return p; };
    u16*   PE16  = (u16*)  alloc(1048576ull*2);
    u16*   E16   = (u16*)  alloc(4ull*1000*128*2);
    u16*   Wt    = (u16*)  alloc(4ull*512*1024*2);
    u16*   Wp16  = (u16*)  alloc(512ull*1024*2);
    u16*   PWT   = (u16*)  alloc(16ull*512*128*2);
    u16*   TQK16 = (u16*)  alloc(16ull*1000*512*2);
    u16*   PEQ16 = (u16*)  alloc(4ull*1024*512*2);
    float* Wcp   = (float*)alloc(4*1024*4);
    float* W0f   = (float*)alloc(1024*4);
    float* vv    = (float*)alloc(2*1024*4);
    float* CQ    = (float*)alloc(16*512*4);
    float* pvb   = (float*)alloc(8*128*4);
    float* Ut    = (float*)alloc(8*1000*4);
    float* cu    = (float*)alloc(8*4);
    float* pu    = (float*)alloc(2*1024*4);
    float* ubuf  = (float*)alloc(2ull*NT*4);
    u16*   Qh    = (u16*)  alloc((size_t)NT*512*2);
    u16*   Kh    = (u16*)  alloc((size_t)NT*512*2);
    float* Pm    = (float*)alloc(32ull*8*1024*4);
    float* Pd    = (float*)alloc(32ull*8*1024*4);
    float* logits= (float*)alloc((size_t)NT*4);
    size_t sChunkBytes = (size_t)SS*SS*2;     // bf16 S
    size_t remain = (ws_size > off) ? (ws_size - off) : 0;
    int NB = (int)(remain / sChunkBytes);
    if (NB > 32) NB = 32;
    if (NB < 1) NB = 1;
    u16* Sbuf = (u16*)(base + off);

    const float alpha = 0.06375954951107036f;   // log2(e)/sqrt(512): exp2 domain

    k_s1<<<8448, 256, 0, stream>>>(E, Wproj, W, W0, Wf, PE16, E16, Wp16, Wt, W0f, Wcp, CQ);
    k_s2<<<2112, 256, 0, stream>>>(Wc, Wproj, W, WV1, WV2, W0f, Wcp, vv);
    k_s3<<<1472, 256, 0, stream>>>(Wp16, Wt, PWT, PE16, PEQ16, W, Wcp, CQ, Wproj, vv, pvb);
    k_s4<<<1057, 256, 0, stream>>>(E16, PWT, PE16, TQK16, Wcp, vv, pvb, Ut, pu, cu);

    for (int h = 0; h < 2; ++h) {
        k_gather<<<8192, 256, 0, stream>>>(cate, cont, TQK16, CQ, PEQ16, Ut, cu, pu, Qh, Kh, ubuf, h);
        for (int b0 = 0; b0 < 32; b0 += NB) {
            int nb = (32 - b0 < NB) ? (32 - b0) : NB;
            k_g_S256<<<16*nb, 512, 0, stream>>>(Qh + (size_t)b0*SS*AT, Kh + (size_t)b0*SS*AT,
                                                Sbuf, alpha, Pm, Pd, b0);
            k_logit<<<nb*64, 1024, 0, stream>>>(Sbuf, Pm, Pd, ubuf + (size_t)h*NT,
                                                logits, (float*)d_out, b0, h);
        }
    }
}

// Round 10
// 335.413 us; speedup vs baseline: 1.0654x; 1.0070x over previous
//
#include <hip/hip_runtime.h>
#include <hip/hip_bf16.h>
#include <math.h>

#define BB    32
#define SS    1024
#define HID   1024
#define AT    512
#define NVOC  1000
#define NT    (BB*SS)

typedef unsigned short u16;
typedef __attribute__((ext_vector_type(8))) short s16x8;   // 8 bf16 (4 VGPRs)
typedef __attribute__((ext_vector_type(4))) float f32x4;   // MFMA acc

__device__ __forceinline__ float bf2f(u16 u) {
    union { unsigned int i; float f; } x; x.i = ((unsigned int)u) << 16; return x.f;
}
__device__ __forceinline__ u16 f2bf(float f) {
    union { float f; unsigned int i; } u; u.f = f;
    unsigned int r = u.i + 0x7fffu + ((u.i >> 16) & 1u);
    return (u16)(r >> 16);
}
__device__ __forceinline__ float4 ld4(const float* p) { return *(const float4*)p; }
__device__ __forceinline__ float4 ld4bf(const u16* p) {
    ushort4 v = *(const ushort4*)p;
    return make_float4(bf2f(v.x), bf2f(v.y), bf2f(v.z), bf2f(v.w));
}
__device__ __forceinline__ void unpack8(uint4 v, float* x) {
    x[0] = bf2f((u16)(v.x & 0xffff)); x[1] = bf2f((u16)(v.x >> 16));
    x[2] = bf2f((u16)(v.y & 0xffff)); x[3] = bf2f((u16)(v.y >> 16));
    x[4] = bf2f((u16)(v.z & 0xffff)); x[5] = bf2f((u16)(v.z >> 16));
    x[6] = bf2f((u16)(v.w & 0xffff)); x[7] = bf2f((u16)(v.w >> 16));
}

// async global->LDS, 16B per lane; LDS dest = uniform base + lane*16 [m97]
__device__ __forceinline__ void gld16(const u16* g, u16* l) {
    __builtin_amdgcn_global_load_lds(
        (const __attribute__((address_space(1))) unsigned int*)g,
        (__attribute__((address_space(3))) unsigned int*)l,
        16, 0, 0);
}

struct Ptrs4f { const float* p[4]; };

__device__ __forceinline__ float blockReduceSum(float x) {
    #pragma unroll
    for (int off = 32; off > 0; off >>= 1) x += __shfl_down(x, off, 64);
    __shared__ float tmp[4];
    int lane = threadIdx.x & 63, wid = threadIdx.x >> 6;
    if (lane == 0) tmp[wid] = x;
    __syncthreads();
    if (threadIdx.x == 0) x = tmp[0] + tmp[1] + tmp[2] + tmp[3];
    return x; // valid on thread 0 only
}
__device__ __forceinline__ float waveReduceSum(float x) {
    #pragma unroll
    for (int off = 32; off > 0; off >>= 1) x += __shfl_down(x, off, 64);
    return x; // valid on lane 0
}

// ================= D1: PE16 + E16 + Wp16 + Wt transpose + W0f + zero(Wcp,CQ) ============
__global__ void k_s1(Ptrs4f E, const float* __restrict__ Wproj, Ptrs4f W,
                     const float* __restrict__ W0, const float* __restrict__ Wf,
                     u16* __restrict__ PE16, u16* __restrict__ E16o, u16* __restrict__ Wp16,
                     u16* __restrict__ Wt, float* __restrict__ W0f,
                     float* __restrict__ Wcp, float* __restrict__ CQ) {
    int blk = blockIdx.x, tid = threadIdx.x;
    if (blk < 2048) {                       // PE table bf16 (fast trig: bf16 output)
        int idx = blk*256 + tid;
        int s = idx >> 9, i = idx & 511;
        const float l2_10000 = 13.287712379549449f;
        float denom = exp2f((2.f * (float)i / 1024.f) * l2_10000);
        float ang = (float)s / denom;
        unsigned int pack = ((unsigned int)f2bf(__cosf(ang)) << 16) | f2bf(__sinf(ang));
        *(unsigned int*)(PE16 + (size_t)s*1024 + 2*i) = pack;
    } else if (blk < 4048) {                // E -> bf16
        int id2 = blk - 2048;
        int f = id2 / 500;
        int i = (id2 % 500)*256 + tid;
        E16o[(size_t)f*128000 + i] = f2bf(E.p[f][i]);
    } else if (blk < 6096) {                // Wproj -> bf16
        int i = (blk - 4048)*256 + tid;
        Wp16[i] = f2bf(Wproj[i]);
    } else if (blk < 8144) {                // W transpose -> Wt (bf16), 32x32 tiles
        int tb = blk - 6096;
        int mat = tb >> 9, t2 = tb & 511;
        int cx = t2 & 15, ry = t2 >> 4;
        int r0 = ry*32, c0 = cx*32;
        const float* in = W.p[mat];
        u16* out = Wt + (size_t)mat*1024*512;
        __shared__ float tt[32][33];
        int tx = tid & 31, ty8 = tid >> 5;
        #pragma unroll
        for (int it = 0; it < 4; ++it)
            tt[ty8 + it*8][tx] = in[(size_t)(r0 + ty8 + it*8)*512 + c0 + tx];
        __syncthreads();
        #pragma unroll
        for (int it = 0; it < 4; ++it)
            out[(size_t)(c0 + ty8 + it*8)*1024 + r0 + tx] = f2bf(tt[tx][ty8 + it*8]);
    } else if (blk < 8400) {                // W0f: wave-per-row, 4 rows/block
        int wave = tid >> 6, lane = tid & 63;
        int row = (blk - 8144)*4 + wave;
        const float* rp = W0 + (size_t)row*1024;
        float a = 0.f;
        #pragma unroll
        for (int i = 0; i < 16; ++i) {
            int j = i*64 + lane;
            a += rp[j] * Wf[j];
        }
        a = waveReduceSum(a);
        if (lane == 0) W0f[row] = a;
    } else {                                // zero Wcp (4096) + CQ (8192)
        int idx = (blk - 8400)*256 + tid;
        if (idx < 4096) Wcp[idx] = 0.f;
        else CQ[idx - 4096] = 0.f;
    }
}

// ================= D2: Wcp atomic j-split (64) + v (2048) =================
__global__ void k_s2(const float* __restrict__ Wc, const float* __restrict__ Wproj,
                     Ptrs4f W, const float* __restrict__ WV1, const float* __restrict__ WV2,
                     const float* __restrict__ W0f, float* __restrict__ Wcp, float* __restrict__ v) {
    int blk = blockIdx.x, tid = threadIdx.x;
    if (blk < 64) {                          // Wcp[c][i] += sum_{j in chunk} Wc*Wproj
        int c = blk >> 4, ic = (blk >> 2) & 3, jc = blk & 3;
        int i = ic*256 + tid;
        float a = 0.f;
        for (int j = jc*128; j < jc*128 + 128; ++j)
            a += Wc[c*512 + j] * Wproj[(size_t)(512 + j)*1024 + i];
        atomicAdd(&Wcp[c*1024 + i], a);
    } else {                                 // v
        int b2 = blk - 64;
        int h = b2 >> 10, i = b2 & 1023;
        const float* WV = h ? WV2 : WV1;
        const float* wf = W0f + h*512;
        float a = 0.f;
        for (int aa = tid; aa < 512; aa += 256) a += WV[(size_t)i*512 + aa] * wf[aa];
        a = blockReduceSum(a);
        if (tid == 0) v[h*1024 + i] = a;
    }
}

// ---------------- MFMA GEMM: C[M,N] = alpha * A[M,K] @ B[N,K]^T (bf16 in) ----------------
// 128^2 4-wave variant kept for the small preprocessing GEMMs (k_s3/k_s4).
__device__ __forceinline__ void cstore(float* p, float v) { *p = v; }
__device__ __forceinline__ void cstore(u16* p, float v)   { *p = f2bf(v); }

template<typename CT, bool CTRANS>
__device__ __forceinline__ void mfma_gemm(const u16* __restrict__ A, const u16* __restrict__ B,
                                          CT* __restrict__ C, int M, int N, int K, float alpha,
                                          int m0, int n0) {
    __shared__ u16 As[128*64];
    __shared__ u16 Bs[128*64];
    const int tid = threadIdx.x;
    const int wave = tid >> 6, lane = tid & 63;
    const int quad = lane >> 4, l16 = lane & 15;
    const int wm = (wave >> 1)*64, wn = (wave & 1)*64;
    const int srow = lane >> 3;
    const int scol = ((lane & 7) ^ srow) * 8;
    f32x4 acc[4][4] = {};

    for (int k0 = 0; k0 < K; k0 += 64) {
        #pragma unroll
        for (int p = 0; p < 4; ++p) {
            int rb = wave*32 + p*8;
            gld16(A + (size_t)(m0 + rb + srow)*K + k0 + scol, As + rb*64);
            gld16(B + (size_t)(n0 + rb + srow)*K + k0 + scol, Bs + rb*64);
        }
        __syncthreads();
        #pragma unroll
        for (int kk = 0; kk < 2; ++kk) {
            s16x8 af[4], bf[4];
            #pragma unroll
            for (int i = 0; i < 4; ++i) {
                int row = wm + i*16 + l16;
                af[i] = *(const s16x8*)(As + row*64 + (((kk*4 + quad) ^ (row & 7)) * 8));
            }
            #pragma unroll
            for (int j = 0; j < 4; ++j) {
                int row = wn + j*16 + l16;
                bf[j] = *(const s16x8*)(Bs + row*64 + (((kk*4 + quad) ^ (row & 7)) * 8));
            }
            #pragma unroll
            for (int i = 0; i < 4; ++i)
                #pragma unroll
                for (int j = 0; j < 4; ++j)
                    acc[i][j] = __builtin_amdgcn_mfma_f32_16x16x32_bf16(af[i], bf[j], acc[i][j], 0, 0, 0);
        }
        __syncthreads();
    }
    // C/D layout: col = lane&15, row = quad*4 + reg  [measured m89/m91]
    #pragma unroll
    for (int i = 0; i < 4; ++i) {
        #pragma unroll
        for (int r = 0; r < 4; ++r) {
            int gm = m0 + wm + i*16 + quad*4 + r;
            if (gm < M) {
                #pragma unroll
                for (int j = 0; j < 4; ++j) {
                    int gn = n0 + wn + j*16 + l16;
                    if (CTRANS) cstore(C + (size_t)gn*M + gm, acc[i][j][r] * alpha);
                    else        cstore(C + (size_t)gm*N + gn, acc[i][j][r] * alpha);
                }
            }
        }
    }
}

// ========= D3: PW GEMM (64) + PEQ GEMM (128) + CQ (256) + pv (1024) =====
__global__ __launch_bounds__(256) void k_s3(const u16* __restrict__ Wp16, const u16* __restrict__ Wt,
                                            u16* __restrict__ PWT,
                                            const u16* __restrict__ PE16, u16* __restrict__ PEQ16,
                                            Ptrs4f W, const float* __restrict__ Wcp, float* __restrict__ CQ,
                                            const float* __restrict__ Wproj, const float* __restrict__ v,
                                            float* __restrict__ pv) {
    int blk = blockIdx.x, tid = threadIdx.x;
    if (blk < 64) {
        int x = blk & 3, z = blk >> 2;
        int f = z >> 2, w = z & 3;
        mfma_gemm<u16,true>(Wp16 + (size_t)f*128*1024, Wt + (size_t)w*512*1024,
                            PWT + (size_t)z*512*128, 128, 512, 1024, 1.f, 0, x*128);
    } else if (blk < 192) {                  // PEQ = PE @ Wt^T  (4 w x 32 tiles)
        int idx = blk - 64;
        int w = idx >> 5, r2 = idx & 31, y = r2 >> 2, x = r2 & 3;
        mfma_gemm<u16,false>(PE16, Wt + (size_t)w*512*1024, PEQ16 + (size_t)w*1024*512,
                             1024, 512, 1024, 1.f, y*128, x*128);
    } else if (blk < 448) {
        int r = blk - 192;
        int ns = r & 1, wc = (r >> 1) & 15, jc = r >> 5;
        int w = wc & 3, c = wc >> 2; int n = ns*256 + tid;
        const float* Ww = W.p[w];
        float a = 0.f;
        for (int j = jc*128; j < jc*128 + 128; ++j) a += Wcp[c*1024 + j] * Ww[(size_t)j*512 + n];
        atomicAdd(&CQ[(size_t)(w*4 + c)*512 + n], a);
    } else {
        int b2 = blk - 448;
        int i = b2 & 127, fh = b2 >> 7; int f = fh >> 1, h = fh & 1;
        const float* row = Wproj + (size_t)(f*128 + i)*1024;
        const float* vh = v + h*1024;
        float a = 0.f;
        for (int j = tid; j < 1024; j += 256) a += row[j] * vh[j];
        a = blockReduceSum(a);
        if (tid == 0) pv[(size_t)fh*128 + i] = a;
    }
}

// ================= D4: TQK GEMMs (512) + compact dots (545) =================
__global__ __launch_bounds__(256) void k_s4(const u16* __restrict__ E16, const u16* __restrict__ PWT,
                                            const u16* __restrict__ PE16,
                                            u16* __restrict__ TQK16,
                                            const float* __restrict__ Wcp, const float* __restrict__ v,
                                            const float* __restrict__ pv,
                                            float* __restrict__ Ut, float* __restrict__ pu, float* __restrict__ cu) {
    int blk = blockIdx.x, tid = threadIdx.x;
    int wave = tid >> 6, lane = tid & 63;
    if (blk < 512) {
        int z = blk >> 5, r = blk & 31, y = r >> 2, x = r & 3;
        int f = z >> 2;
        mfma_gemm<u16,false>(E16 + (size_t)f*128000, PWT + (size_t)z*512*128,
                   TQK16 + (size_t)z*1000*512, 1000, 512, 128, 1.f, y*128, x*128);
        return;
    }
    int id = blk - 512;
    if (id < 32) {                               // Ut: one thread per (f,h,r) dot, 128-dim
        int d = id*256 + tid;
        if (d < 8000) {
            int f = d / 2000, h = (d / 1000) & 1, r = d % 1000;
            const u16* er = E16 + ((size_t)f*1000 + r)*128;
            const float* pvp = pv + (size_t)(f*2 + h)*128;
            float a = 0.f;
            #pragma unroll
            for (int q = 0; q < 16; ++q) {
                float xv[8];
                unpack8(*(const uint4*)(er + q*8), xv);
                #pragma unroll
                for (int e = 0; e < 8; ++e) a += xv[e] * pvp[q*8 + e];
            }
            Ut[(size_t)(f*2 + h)*1000 + r] = a;
        }
    } else if (id < 544) {                       // pu: wave per dot, 1024-dim
        int d = (id - 32)*4 + wave;              // 512 blocks x 4 waves = 2048 dots
        int h = d >> 10, s = d & 1023;
        float a = 0.f;
        #pragma unroll
        for (int half = 0; half < 2; ++half) {
            int k = half*512 + lane*8;
            float xv[8];
            unpack8(*(const uint4*)(PE16 + (size_t)s*1024 + k), xv);
            float4 b0 = ld4(v + h*1024 + k), b1 = ld4(v + h*1024 + k + 4);
            a += xv[0]*b0.x + xv[1]*b0.y + xv[2]*b0.z + xv[3]*b0.w
               + xv[4]*b1.x + xv[5]*b1.y + xv[6]*b1.z + xv[7]*b1.w;
        }
        a = waveReduceSum(a);
        if (lane == 0) pu[h*1024 + s] = a;
    } else {                                     // cu: 8 dots, waves do 2 each
        #pragma unroll
        for (int rep = 0; rep < 2; ++rep) {
            int d = wave*2 + rep;                // 0..7
            int h = d >> 2, c = d & 3;
            float a = 0.f;
            #pragma unroll
            for (int i = 0; i < 16; ++i) {
                int j = i*64 + lane;
                a += Wcp[c*1024 + j] * v[h*1024 + j];
            }
            a = waveReduceSum(a);
            if (lane == 0) cu[h*4 + c] = a;
        }
    }
}

// ================= scores GEMM, 256^2 tile / 8 waves / 8-phase schedule (R2/R6, 52us) ====
__global__ __launch_bounds__(512, 2) void k_g_S256(
        const u16* __restrict__ Q, const u16* __restrict__ K,
        u16* __restrict__ Sb, float alpha,
        float* __restrict__ Pm, float* __restrict__ Pd, int b0) {
    __shared__ u16 As[2][16384];       // 2 x 256x64 bf16 = 64 KiB
    __shared__ u16 Bs[2][16384];       // 64 KiB  (total 128 KiB -> 1 block/CU, 8 waves)
    const int tid = threadIdx.x;
    const int wave = tid >> 6, lane = tid & 63;
    const int quad = lane >> 4, l16 = lane & 15;
    const int wm = wave >> 2, wn = wave & 3;         // 2M x 4N wave grid

    // bijective XCD swizzle (m204)
    const int nwg = (int)gridDim.x;
    int fblk = (int)blockIdx.x;
    int qq = nwg >> 3, rr = nwg & 7;
    int xcd = fblk & 7, idx = fblk >> 3;
    int swz = (xcd < rr ? xcd*(qq + 1) : rr*(qq + 1) + (xcd - rr)*qq) + idx;
    int b = swz >> 4, tile = swz & 15;
    int m0 = (tile >> 2) << 8, n0 = (tile & 3) << 8;

    const u16* __restrict__ Ab = Q + (size_t)b*SS*AT;
    const u16* __restrict__ Bb = K + (size_t)b*SS*AT;
    u16* __restrict__ C = Sb + (size_t)b*SS*SS;

    const int srow = lane >> 3;                 // 0..7
    const int scol = ((lane & 7) ^ srow) * 8;   // XOR k-chunk pre-swizzle (conflict-free)

    f32x4 acc[8][4] = {};

    // stage one 64-row chunk (q=0..3) of A or B for K-tile kt into buf kt&1 (1 gld16/thread)
    auto stageA = [&](int kt, int q) {
        gld16(Ab + (size_t)(m0 + q*64 + wave*8 + srow)*AT + kt*64 + scol,
              &As[kt & 1][q*4096 + wave*512]);
    };
    auto stageB = [&](int kt, int q) {
        gld16(Bb + (size_t)(n0 + q*64 + wave*8 + srow)*AT + kt*64 + scol,
              &Bs[kt & 1][q*4096 + wave*512]);
    };

    s16x8 af[4][2];          // A frags for current ih-half (reloaded at P0/P2)
    s16x8 bf[4][2];          // B frags, whole K-tile (bf[0..1] at P0, bf[2..3] at P1)

    auto readA = [&](int c, int ih) {
        #pragma unroll
        for (int i2 = 0; i2 < 4; ++i2) {
            int row = wm*128 + (ih*4 + i2)*16 + l16;
            #pragma unroll
            for (int kk = 0; kk < 2; ++kk)
                af[i2][kk] = *(const s16x8*)(&As[c][row*64 + (((kk*4 + quad) ^ (row & 7)) * 8)]);
        }
    };
    auto readB2 = [&](int c, int jh) {
        #pragma unroll
        for (int j2 = 0; j2 < 2; ++j2) {
            int j = jh*2 + j2;
            int row = wn*64 + j*16 + l16;
            #pragma unroll
            for (int kk = 0; kk < 2; ++kk)
                bf[j][kk] = *(const s16x8*)(&Bs[c][row*64 + (((kk*4 + quad) ^ (row & 7)) * 8)]);
        }
    };
    auto mma16 = [&](int ih, int jh) {         // one C-quadrant x K=64: 16 MFMA
        __builtin_amdgcn_s_setprio(1);
        #pragma unroll
        for (int i2 = 0; i2 < 4; ++i2)
            #pragma unroll
            for (int j2 = 0; j2 < 2; ++j2) {
                int i = ih*4 + i2, j = jh*2 + j2;
                acc[i][j] = __builtin_amdgcn_mfma_f32_16x16x32_bf16(af[i2][0], bf[j][0], acc[i][j], 0, 0, 0);
                acc[i][j] = __builtin_amdgcn_mfma_f32_16x16x32_bf16(af[i2][1], bf[j][1], acc[i][j], 0, 0, 0);
            }
        __builtin_amdgcn_s_setprio(0);
    };
    auto midsync = [&]() {                      // barrier, own-reads done, pin (rule 18)
        __builtin_amdgcn_s_barrier();
        asm volatile("s_waitcnt lgkmcnt(0)" ::: "memory");
        __builtin_amdgcn_sched_barrier(0);
    };

    // prologue: tile0 all 8 chunks + tile1's first 6 (A1,A3 of tile1 go at t0.P0)
    #pragma unroll
    for (int q = 0; q < 4; ++q) stageA(0, q);
    #pragma unroll
    for (int q = 0; q < 4; ++q) stageB(0, q);
    stageA(1, 0); stageA(1, 2);
    stageB(1, 0); stageB(1, 1); stageB(1, 2); stageB(1, 3);
    asm volatile("s_waitcnt vmcnt(6)" ::: "memory");   // tile0 (oldest 8) landed
    __builtin_amdgcn_s_barrier();

    #pragma unroll
    for (int t = 0; t < 8; ++t) {
        const int c = t & 1;
        // ---- P0: quadrant (ih=0, jh=0); 12 ds_reads; stage (t+1) A1,A3 -> idle buffer
        readA(c, 0);
        readB2(c, 0);
        if (t <= 6) { stageA(t + 1, 1); stageA(t + 1, 3); }
        midsync();
        mma16(0, 0);
        __builtin_amdgcn_s_barrier();
        // ---- P1: quadrant (0,1); 4 ds_reads; stage (t+2) A0,A2 (free since end P0)
        readB2(c, 1);
        if (t <= 5) { stageA(t + 2, 0); stageA(t + 2, 2); }
        midsync();
        mma16(0, 1);
        __builtin_amdgcn_s_barrier();
        // ---- P2: quadrant (1,0); 8 ds_reads; stage (t+2) B0,B1 (B free since end P1)
        readA(c, 1);
        if (t <= 5) { stageB(t + 2, 0); stageB(t + 2, 1); }
        midsync();
        mma16(1, 0);
        __builtin_amdgcn_s_barrier();
        // ---- P3: quadrant (1,1); stage (t+2) B2,B3; tile-boundary counted vmcnt
        if (t <= 5) { stageB(t + 2, 2); stageB(t + 2, 3); }
        midsync();
        mma16(1, 1);
        if (t <= 5)      asm volatile("s_waitcnt vmcnt(6)" ::: "memory");  // t+1 landed
        else if (t == 6) asm volatile("s_waitcnt vmcnt(0)" ::: "memory");  // tile7 landed
        __builtin_amdgcn_sched_barrier(0);
        __builtin_amdgcn_s_barrier();
    }

    // epilogue: quantize once, permuted 8B stores, per-tile column max+sum stats
    #pragma unroll
    for (int i = 0; i < 8; ++i) {
        #pragma unroll
        for (int r = 0; r < 4; ++r) {
            int gm = m0 + wm*128 + i*16 + quad*4 + r;
            u16 q0 = f2bf(acc[i][0][r] * alpha);
            u16 q1 = f2bf(acc[i][1][r] * alpha);
            u16 q2 = f2bf(acc[i][2][r] * alpha);
            u16 q3 = f2bf(acc[i][3][r] * alpha);
            acc[i][0][r] = bf2f(q0); acc[i][1][r] = bf2f(q1);
            acc[i][2][r] = bf2f(q2); acc[i][3][r] = bf2f(q3);
            unsigned int lo = (unsigned int)q0 | ((unsigned int)q1 << 16);
            unsigned int hi = (unsigned int)q2 | ((unsigned int)q3 << 16);
            *(uint2*)(C + (size_t)gm*SS + n0 + wn*64 + l16*4) = make_uint2(lo, hi);
        }
    }
    // per-wave stats over its 128 rows; LDS (loop done) reused for the combine
    float* sM = (float*)&As[0][0];
    float* sS = (float*)&Bs[0][0];
    #pragma unroll
    for (int j = 0; j < 4; ++j) {
        float mx = -3.4e38f;
        #pragma unroll
        for (int i = 0; i < 8; ++i)
            #pragma unroll
            for (int r = 0; r < 4; ++r) mx = fmaxf(mx, acc[i][j][r]);
        mx = fmaxf(mx, __shfl_xor(mx, 16, 64));
        mx = fmaxf(mx, __shfl_xor(mx, 32, 64));
        float sm = 0.f;
        #pragma unroll
        for (int i = 0; i < 8; ++i)
            #pragma unroll
            for (int r = 0; r < 4; ++r) sm += exp2f(acc[i][j][r] - mx);
        sm += __shfl_xor(sm, 16, 64);
        sm += __shfl_xor(sm, 32, 64);
        if (quad == 0) { sM[wave*64 + j*16 + l16] = mx; sS[wave*64 + j*16 + l16] = sm; }
    }
    __syncthreads();
    if (tid < 256) {                     // combine the 2 row-half partials per column
        int c = tid, wq = c >> 6, cc = c & 63;
        float ma = sM[wq*64 + cc],       sa = sS[wq*64 + cc];
        float mb = sM[(4 + wq)*64 + cc], sb2 = sS[(4 + wq)*64 + cc];
        float mm = fmaxf(ma, mb);
        float ss = sa * exp2f(ma - mm) + sb2 * exp2f(mb - mm);
        size_t po = ((size_t)(b0 + b)*4 + (m0 >> 8))*1024;
        Pm[po + n0 + c] = mm;
        Pd[po + n0 + c] = ss;
    }
}

// ---------------- shared gather body (per token t, col-slot, slice g, head h) -----------
// CQ reads vectorized to float4; summation expression token-for-token identical to R6/R8,
// so bf16 outputs are bit-identical.
__device__ __forceinline__ void gather_body(
        const int* __restrict__ cate, const float* __restrict__ cont,
        const u16* __restrict__ TQK, const float* __restrict__ CQ,
        const u16* __restrict__ PEQ, const float* __restrict__ Ut,
        const float* __restrict__ cu, const float* __restrict__ pu,
        u16* __restrict__ Qh, u16* __restrict__ Kh, float* __restrict__ u,
        int h, size_t t, int cslot, int g, bool writeU) {
    int s = (int)(t & 1023);
    int4 cc = *(const int4*)(cate + t*4);
    float4 cv = ld4(cont + t*4);
    int n = g*64 + cslot*8;
    #pragma unroll
    for (int e = 0; e < 2; ++e) {                   // 0=Q, 1=K
        int w = 2*h + e;
        const u16* t0 = TQK + ((size_t)(0*4  + w)*1000 + cc.x)*512 + n;
        const u16* t1 = TQK + ((size_t)(1*4  + w)*1000 + cc.y)*512 + n;
        const u16* t2 = TQK + ((size_t)(2*4  + w)*1000 + cc.z)*512 + n;
        const u16* t3 = TQK + ((size_t)(3*4  + w)*1000 + cc.w)*512 + n;
        const u16* pq = PEQ + ((size_t)w*1024 + s)*512 + n;
        const float* cq = CQ + (size_t)w*2048 + n;
        float a0[8], a1[8], a2[8], a3[8], ap[8];
        unpack8(*(const uint4*)t0, a0); unpack8(*(const uint4*)t1, a1);
        unpack8(*(const uint4*)t2, a2); unpack8(*(const uint4*)t3, a3);
        unpack8(*(const uint4*)pq, ap);
        float q0[8], q1[8], q2[8], q3[8];
        *(float4*)&q0[0] = ld4(cq);        *(float4*)&q0[4] = ld4(cq + 4);
        *(float4*)&q1[0] = ld4(cq + 512);  *(float4*)&q1[4] = ld4(cq + 516);
        *(float4*)&q2[0] = ld4(cq + 1024); *(float4*)&q2[4] = ld4(cq + 1028);
        *(float4*)&q3[0] = ld4(cq + 1536); *(float4*)&q3[4] = ld4(cq + 1540);
        unsigned int pack[4];
        #pragma unroll
        for (int jp = 0; jp < 4; ++jp) {
            float x0, x1;
            #pragma unroll
            for (int half = 0; half < 2; ++half) {
                int j = jp*2 + half;
                float x = a0[j] + a1[j] + a2[j] + a3[j] + ap[j]
                        + cv.x*q0[j] + cv.y*q1[j] + cv.z*q2[j] + cv.w*q3[j];
                if (half == 0) x0 = x; else x1 = x;
            }
            pack[jp] = ((unsigned int)f2bf(x1) << 16) | f2bf(x0);
        }
        u16* op = (e ? Kh : Qh) + t*512 + n;
        *(uint4*)op = make_uint4(pack[0], pack[1], pack[2], pack[3]);
    }
    if (writeU) {
        float uu = pu[h*1024 + s]
                 + Ut[(0*2 + h)*1000 + cc.x] + Ut[(1*2 + h)*1000 + cc.y]
                 + Ut[(2*2 + h)*1000 + cc.z] + Ut[(3*2 + h)*1000 + cc.w]
                 + cv.x*cu[h*4+0] + cv.y*cu[h*4+1] + cv.z*cu[h*4+2] + cv.w*cu[h*4+3];
        u[(size_t)h*NT + t] = uu;
    }
}

// ---------------- shared logit body (16 rows, 1024 threads, inline stat combine) --------
__device__ __forceinline__ void logit_body(
        const u16* __restrict__ Sb,
        const float* __restrict__ Pm, const float* __restrict__ Pd,
        const float* __restrict__ u,
        float* __restrict__ logits, float* __restrict__ out,
        int b0, int mode, int blk, int nblk, float* wsmBase) {
    float (*wsm)[128] = (float (*)[128])wsmBase;
    int wave = threadIdx.x >> 6, lane = threadIdx.x & 63;
    size_t bi = (size_t)(nblk - 1 - blk);               // reverse: S-tail still in L2
    size_t tl0 = bi*16;
    size_t tabs0 = (size_t)b0*1024 + tl0;
    int ab = (int)(tabs0 >> 10);                        // absolute batch
    {   // inline stats: one column per thread (identical math to k_stats_combine)
        int k = threadIdx.x;
        float mx = -3.4e38f;
        #pragma unroll
        for (int mt = 0; mt < 4; ++mt) mx = fmaxf(mx, Pm[((size_t)ab*4 + mt)*1024 + k]);
        float dd = 0.f;
        #pragma unroll
        for (int mt = 0; mt < 4; ++mt) dd += Pd[((size_t)ab*4 + mt)*1024 + k]
                                           * exp2f(Pm[((size_t)ab*4 + mt)*1024 + k] - mx);
        int q = (k & ~63) | (((k & 15) << 2) | ((k & 63) >> 4));
        wsm[q & 7][q >> 3] = u[(size_t)ab*1024 + k] / dd * exp2f(-mx);
    }
    __syncthreads();
    size_t tl = tl0 + wave;
    size_t tabs = tabs0 + wave;
    const u16* row = Sb + tl*1024;
    float acc = 0.f;
    #pragma unroll
    for (int half = 0; half < 2; ++half) {
        int k = lane*8 + half*512;
        int li = lane + half*64;
        float sv[8];
        unpack8(*(const uint4*)(row + k), sv);
        acc += exp2f(sv[0])*wsm[0][li] + exp2f(sv[1])*wsm[1][li]
             + exp2f(sv[2])*wsm[2][li] + exp2f(sv[3])*wsm[3][li]
             + exp2f(sv[4])*wsm[4][li] + exp2f(sv[5])*wsm[5][li]
             + exp2f(sv[6])*wsm[6][li] + exp2f(sv[7])*wsm[7][li];
    }
    acc = waveReduceSum(acc);
    if (lane == 0) {
        if (mode == 0) logits[tabs] = acc;
        else {
            float x = logits[tabs] + acc;
            out[tabs] = 1.f / (1.f + expf(-x));
        }
    }
}

// ---------------- gather standalone (head h): 256 thr, 32 tokens/block ----------------
__global__ __launch_bounds__(256) void k_gather(
                         const int* __restrict__ cate, const float* __restrict__ cont,
                         const u16* __restrict__ TQK, const float* __restrict__ CQ,
                         const u16* __restrict__ PEQ, const float* __restrict__ Ut,
                         const float* __restrict__ cu, const float* __restrict__ pu,
                         u16* __restrict__ Qh, u16* __restrict__ Kh,
                         float* __restrict__ u, int h) {
    int tid = threadIdx.x;
    int g = blockIdx.x & 7;                         // col-slice -> XCD pin
    size_t t = (size_t)(blockIdx.x >> 3)*32 + (tid >> 3);
    gather_body(cate, cont, TQK, CQ, PEQ, Ut, cu, pu, Qh, Kh, u, h,
                t, tid & 7, g, g == 0 && (tid & 7) == 0);
}

// ---------------- logit standalone: 1024 thr, 16 rows/block ----------------
__global__ __launch_bounds__(1024) void k_logit(const u16* __restrict__ Sb,
                        const float* __restrict__ Pm, const float* __restrict__ Pd,
                        const float* __restrict__ u,
                        float* __restrict__ logits, float* __restrict__ out,
                        int b0, int mode) {
    __shared__ float wsm[8][128];
    logit_body(Sb, Pm, Pd, u, logits, out, b0, mode, (int)blockIdx.x, (int)gridDim.x,
               &wsm[0][0]);
}

// ---------------- fused: logit(h=0, all 32 batches) || gather(h=1) ----------------
// Independent work: logit0 reads {Sbuf, Pm/Pd, ubuf[0..NT)}, writes logits; gather1
// reads tables, writes {Qh, Kh, ubuf[NT..2NT)} (Qh/Kh free: S256(h0) consumed them).
// Blocks [0,2048) = logit; [2048,4096) = gather at 128 tokens/block (1024 thr).
// gather's XCD slice-pin preserved: 2048 % 8 == 0. Block-uniform branch (no divergent
// __syncthreads).
__global__ __launch_bounds__(1024) void k_logit_gather(
        const u16* __restrict__ Sb,
        const float* __restrict__ Pm, const float* __restrict__ Pd,
        const float* __restrict__ ubuf,
        float* __restrict__ logits, float* __restrict__ out,
        const int* __restrict__ cate, const float* __restrict__ cont,
        const u16* __restrict__ TQK, const float* __restrict__ CQ,
        const u16* __restrict__ PEQ, const float* __restrict__ Ut,
        const float* __restrict__ cu, const float* __restrict__ pu,
        u16* __restrict__ Qh, u16* __restrict__ Kh, float* __restrict__ ub) {
    __shared__ float wsm[8][128];
    int blk = (int)blockIdx.x;
    if (blk < 2048) {
        logit_body(Sb, Pm, Pd, ubuf, logits, out, 0, 0, blk, 2048, &wsm[0][0]);
    } else {
        int gb = blk - 2048;
        int tid = threadIdx.x;
        int g = gb & 7;
        size_t t = (size_t)(gb >> 3)*128 + (tid >> 3);
        gather_body(cate, cont, TQK, CQ, PEQ, Ut, cu, pu, Qh, Kh, ub, 1,
                    t, tid & 7, g, g == 0 && (tid & 7) == 0);
    }
}

extern "C" void kernel_launch(void* const* d_in, const int* in_sizes, int n_in,
                              void* d_out, int out_size, void* d_ws, size_t ws_size,
                              hipStream_t stream) {
    const int*   cate = (const int*)d_in[0];
    const float* cont = (const float*)d_in[1];
    Ptrs4f E; E.p[0] = (const float*)d_in[4]; E.p[1] = (const float*)d_in[5];
              E.p[2] = (const float*)d_in[6]; E.p[3] = (const float*)d_in[7];
    const float* Wc    = (const float*)d_in[8];
    const float* Wproj = (const float*)d_in[9];
    Ptrs4f W; W.p[0] = (const float*)d_in[10];  // WQ1
              W.p[1] = (const float*)d_in[11];  // WK1
              W.p[2] = (const float*)d_in[13];  // WQ2
              W.p[3] = (const float*)d_in[14];  // WK2
    const float* WV1 = (const float*)d_in[12];
    const float* WV2 = (const float*)d_in[15];
    const float* W0  = (const float*)d_in[16];
    const float* Wf  = (const float*)d_in[17];

    char* base = (char*)d_ws;
    size_t off = 0;
    auto alloc = [&](size_t bytes) { void* p = base + off; off += (bytes + 255) & ~(size_t)255; return p; };
    u16*   PE16  = (u16*)  alloc(1048576ull*2);
    u16*   E16   = (u16*)  alloc(4ull*1000*128*2);
    u16*   Wt    = (u16*)  alloc(4ull*512*1024*2);
    u16*   Wp16  = (u16*)  alloc(512ull*1024*2);
    u16*   PWT   = (u16*)  alloc(16ull*512*128*2);
    u16*   TQK16 = (u16*)  alloc(16ull*1000*512*2);
    u16*   PEQ16 = (u16*)  alloc(4ull*1024*512*2);
    float* Wcp   = (float*)alloc(4*1024*4);
    float* W0f   = (float*)alloc(1024*4);
    float* vv    = (float*)alloc(2*1024*4);
    float* CQ    = (float*)alloc(16*512*4);
    float* pvb   = (float*)alloc(8*128*4);
    float* Ut    = (float*)alloc(8*1000*4);
    float* cu    = (float*)alloc(8*4);
    float* pu    = (float*)alloc(2*1024*4);
    float* ubuf  = (float*)alloc(2ull*NT*4);
    u16*   Qh    = (u16*)  alloc((size_t)NT*512*2);
    u16*   Kh    = (u16*)  alloc((size_t)NT*512*2);
    float* Pm    = (float*)alloc(32ull*8*1024*4);
    float* Pd    = (float*)alloc(32ull*8*1024*4);
    float* logits= (float*)alloc((size_t)NT*4);
    size_t sChunkBytes = (size_t)SS*SS*2;     // bf16 S
    size_t remain = (ws_size > off) ? (ws_size - off) : 0;
    int NB = (int)(remain / sChunkBytes);
    if (NB > 32) NB = 32;
    if (NB < 1) NB = 1;
    u16* Sbuf = (u16*)(base + off);

    const float alpha = 0.06375954951107036f;   // log2(e)/sqrt(512): exp2 domain

    k_s1<<<8448, 256, 0, stream>>>(E, Wproj, W, W0, Wf, PE16, E16, Wp16, Wt, W0f, Wcp, CQ);
    k_s2<<<2112, 256, 0, stream>>>(Wc, Wproj, W, WV1, WV2, W0f, Wcp, vv);
    k_s3<<<1472, 256, 0, stream>>>(Wp16, Wt, PWT, PE16, PEQ16, W, Wcp, CQ, Wproj, vv, pvb);
    k_s4<<<1057, 256, 0, stream>>>(E16, PWT, PE16, TQK16, Wcp, vv, pvb, Ut, pu, cu);

    if (NB == 32) {
        // head 0
        k_gather<<<8192, 256, 0, stream>>>(cate, cont, TQK16, CQ, PEQ16, Ut, cu, pu, Qh, Kh, ubuf, 0);
        k_g_S256<<<512, 512, 0, stream>>>(Qh, Kh, Sbuf, alpha, Pm, Pd, 0);
        // logit(h0) overlapped with gather(h1)
        k_logit_gather<<<4096, 1024, 0, stream>>>(Sbuf, Pm, Pd, ubuf, logits, (float*)d_out,
                                                  cate, cont, TQK16, CQ, PEQ16, Ut, cu, pu,
                                                  Qh, Kh, ubuf);
        // head 1
        k_g_S256<<<512, 512, 0, stream>>>(Qh, Kh, Sbuf, alpha, Pm, Pd, 0);
        k_logit<<<2048, 1024, 0, stream>>>(Sbuf, Pm, Pd, ubuf + NT, logits, (float*)d_out, 0, 1);
    } else {
        for (int h = 0; h < 2; ++h) {
            k_gather<<<8192, 256, 0, stream>>>(cate, cont, TQK16, CQ, PEQ16, Ut, cu, pu, Qh, Kh, ubuf, h);
            for (int b0 = 0; b0 < 32; b0 += NB) {
                int nb = (32 - b0 < NB) ? (32 - b0) : NB;
                k_g_S256<<<16*nb, 512, 0, stream>>>(Qh + (size_t)b0*SS*AT, Kh + (size_t)b0*SS*AT,
                                                    Sbuf, alpha, Pm, Pd, b0);
                k_logit<<<nb*64, 1024, 0, stream>>>(Sbuf, Pm, Pd, ubuf + (size_t)h*NT,
                                                    logits, (float*)d_out, b0, h);
            }
        }
    }
}